// Round 6
// baseline (1060.918 us; speedup 1.0000x reference)
//
#include <hip/hip_runtime.h>
#include <hip/hip_bf16.h>
#include <math.h>

#define T     2048
#define HID   1536
#define NH    12
#define DK    128
#define DV    128
#define CONVK 4
#define CH    64
#define NC    32

typedef __attribute__((ext_vector_type(8))) short bf16x8;
typedef __attribute__((ext_vector_type(4))) float floatx4;

__device__ __forceinline__ float siluf(float x) {
    return x / (1.0f + __expf(-x));
}
__device__ __forceinline__ unsigned short f2bf(float f) {
    union { __hip_bfloat16 b; unsigned short u; } cv;
    cv.b = __float2bfloat16(f);
    return cv.u;
}
__device__ __forceinline__ float bf2f(unsigned short u) {
    union { unsigned int u; float f; } cv;
    cv.u = ((unsigned int)u) << 16;
    return cv.f;
}
__device__ __forceinline__ void gl_lds16(const void* g, void* l) {
    __builtin_amdgcn_global_load_lds(
        (const __attribute__((address_space(1))) void*)g,
        (__attribute__((address_space(3))) void*)l, 16, 0, 0);
}

// ---------------------------------------------------------------------------
// split fp32 -> (hi, lo) bf16 pair, vectorized x4
// ---------------------------------------------------------------------------
__global__ __launch_bounds__(256) void splitcast_kernel(const float* __restrict__ s,
                                                        unsigned short* __restrict__ hi,
                                                        unsigned short* __restrict__ lo,
                                                        int n4) {
    int i = blockIdx.x * 256 + threadIdx.x;
    if (i >= n4) return;
    float4 x = ((const float4*)s)[i];
    ushort4 h, l;
    h.x = f2bf(x.x); l.x = f2bf(x.x - bf2f(h.x));
    h.y = f2bf(x.y); l.y = f2bf(x.y - bf2f(h.y));
    h.z = f2bf(x.z); l.z = f2bf(x.z - bf2f(h.z));
    h.w = f2bf(x.w); l.w = f2bf(x.w - bf2f(h.w));
    ((ushort4*)hi)[i] = h;
    ((ushort4*)lo)[i] = l;
}

// ---------------------------------------------------------------------------
// transpose + split: src (K x N fp32) -> hi/lo (N x K bf16). K%32==0.
// ---------------------------------------------------------------------------
__global__ __launch_bounds__(256) void transsplit_kernel(const float* __restrict__ src,
                                                         unsigned short* __restrict__ hi,
                                                         unsigned short* __restrict__ lo,
                                                         int K, int N) {
    __shared__ float tile[32][33];
    const int k0 = blockIdx.y * 32, n0 = blockIdx.x * 32;
    const int tx = threadIdx.x, ty = threadIdx.y;
#pragma unroll
    for (int r = 0; r < 4; ++r) {
        int kk = k0 + ty + 8 * r, nn = n0 + tx;
        tile[ty + 8 * r][tx] = (nn < N) ? src[(size_t)kk * N + nn] : 0.0f;
    }
    __syncthreads();
#pragma unroll
    for (int r = 0; r < 4; ++r) {
        int nn = n0 + ty + 8 * r, kk = k0 + tx;
        if (nn < N) {
            float x = tile[tx][ty + 8 * r];
            unsigned short h = f2bf(x);
            hi[(size_t)nn * K + kk] = h;
            lo[(size_t)nn * K + kk] = f2bf(x - bf2f(h));
        }
    }
}

// ---------------------------------------------------------------------------
// Split-bf16 MFMA GEMM (effectively fp32): C = (Ah+Al)(Bh+Bl)^T, lo*lo dropped.
// ---------------------------------------------------------------------------
template<int EPI>
__global__ __launch_bounds__(256)
void mgemm(const unsigned short* __restrict__ Ah, const unsigned short* __restrict__ Al,
           const unsigned short* __restrict__ Bh, const unsigned short* __restrict__ Bl,
           int K, int N, float* __restrict__ C, unsigned short* __restrict__ Cb,
           float* __restrict__ qf, float* __restrict__ kf, float* __restrict__ vf,
           unsigned short* __restrict__ gsilb, float* __restrict__ w1f,
           float* __restrict__ bgraw)
{
    __shared__ unsigned short AsH[4096], AsL[4096], BsH[4096], BsL[4096];
    const int tid = threadIdx.x;
    const int wave = tid >> 6, lane = tid & 63;
    const int wr = wave >> 1, wc = wave & 1;
    const int lm = lane & 15, lq = lane >> 4;
    const int rowBase = blockIdx.y * 128, colBase = blockIdx.x * 128;

    floatx4 acc[4][4];
#pragma unroll
    for (int i = 0; i < 4; ++i)
#pragma unroll
        for (int j = 0; j < 4; ++j) acc[i][j] = (floatx4){0.f, 0.f, 0.f, 0.f};

    const int mt0 = wave * 2, mt1 = wave * 2 + 1;
    const size_t aOff0 = (size_t)(rowBase + mt0 * 16 + lm) * K + lq * 8;
    const size_t aOff1 = (size_t)(rowBase + mt1 * 16 + lm) * K + lq * 8;
    const size_t bOff0 = (size_t)(colBase + mt0 * 16 + lm) * K + lq * 8;
    const size_t bOff1 = (size_t)(colBase + mt1 * 16 + lm) * K + lq * 8;

    for (int k0 = 0; k0 < K; k0 += 32) {
        gl_lds16(Ah + aOff0 + k0, &AsH[mt0 * 512]);
        gl_lds16(Ah + aOff1 + k0, &AsH[mt1 * 512]);
        gl_lds16(Al + aOff0 + k0, &AsL[mt0 * 512]);
        gl_lds16(Al + aOff1 + k0, &AsL[mt1 * 512]);
        gl_lds16(Bh + bOff0 + k0, &BsH[mt0 * 512]);
        gl_lds16(Bh + bOff1 + k0, &BsH[mt1 * 512]);
        gl_lds16(Bl + bOff0 + k0, &BsL[mt0 * 512]);
        gl_lds16(Bl + bOff1 + k0, &BsL[mt1 * 512]);
        __syncthreads();
        bf16x8 ah[4], al[4], bh[4], bl[4];
#pragma unroll
        for (int i = 0; i < 4; ++i) {
            ah[i] = *(const bf16x8*)&AsH[(wr * 4 + i) * 512 + lane * 8];
            al[i] = *(const bf16x8*)&AsL[(wr * 4 + i) * 512 + lane * 8];
            bh[i] = *(const bf16x8*)&BsH[(wc * 4 + i) * 512 + lane * 8];
            bl[i] = *(const bf16x8*)&BsL[(wc * 4 + i) * 512 + lane * 8];
        }
#pragma unroll
        for (int mi = 0; mi < 4; ++mi)
#pragma unroll
            for (int ni = 0; ni < 4; ++ni) {
                acc[mi][ni] = __builtin_amdgcn_mfma_f32_16x16x32_bf16(
                    ah[mi], bh[ni], acc[mi][ni], 0, 0, 0);
                acc[mi][ni] = __builtin_amdgcn_mfma_f32_16x16x32_bf16(
                    ah[mi], bl[ni], acc[mi][ni], 0, 0, 0);
                acc[mi][ni] = __builtin_amdgcn_mfma_f32_16x16x32_bf16(
                    al[mi], bh[ni], acc[mi][ni], 0, 0, 0);
            }
        __syncthreads();
    }

#pragma unroll
    for (int mi = 0; mi < 4; ++mi)
#pragma unroll
        for (int ni = 0; ni < 4; ++ni) {
            const int col = colBase + wc * 64 + ni * 16 + lm;
#pragma unroll
            for (int r = 0; r < 4; ++r) {
                const int row = rowBase + wr * 64 + mi * 16 + lq * 4 + r;
                const float x = acc[mi][ni][r];
                if (EPI == 0) {
                    C[(size_t)row * N + col] = x;
                } else if (EPI == 3) {
                    Cb[(size_t)row * N + col] = f2bf(x);
                } else if (EPI == 1) {
                    if (col < 1536)       qf[(size_t)row * 1536 + col] = siluf(x);
                    else if (col < 3072)  kf[(size_t)row * 1536 + col - 1536] = siluf(x);
                    else                  vf[(size_t)row * 1536 + col - 3072] = x;
                } else {  // EPI == 2
                    if (col < 1536)       gsilb[(size_t)row * 1536 + col] = f2bf(siluf(x));
                    else if (col < 1728)  w1f[(size_t)row * 192 + col - 1536] = siluf(x);
                    else if (col < 1752)  bgraw[(size_t)row * 24 + col - 1728] = x;
                }
            }
        }
}

// ---------------------------------------------------------------------------
__global__ __launch_bounds__(256) void bg2_kernel(const float* __restrict__ bgraw,
                                                  const float* __restrict__ A_log,
                                                  const float* __restrict__ dt_bias,
                                                  float* __restrict__ beta,
                                                  float* __restrict__ g) {
    int idx = blockIdx.x * 256 + threadIdx.x;
    if (idx >= T * 24) return;
    int t = idx / 24, c = idx % 24;
    float x = bgraw[idx];
    if (c < 12) {
        beta[t * NH + c] = 1.0f / (1.0f + __expf(-x));
    } else {
        int h = c - 12;
        float y = x + dt_bias[h];
        float sp = (y > 20.0f) ? y : log1pf(__expf(y));
        g[t * NH + h] = -__expf(A_log[h]) * sp;
    }
}

// ---------------------------------------------------------------------------
__global__ __launch_bounds__(256) void conv_kernel(const float* __restrict__ vpre,
                                                   const unsigned short* __restrict__ w,
                                                   float* __restrict__ v) {
    const int idx = blockIdx.x * 256 + threadIdx.x;
    if (idx >= T * HID) return;
    const int t = idx / HID, d = idx % HID;
    const ushort4 wv = *(const ushort4*)(w + (size_t)t * (HID * CONVK) + d * 4);
    const float w4[4] = { bf2f(wv.x), bf2f(wv.y), bf2f(wv.z), bf2f(wv.w) };
    float acc = 0.0f;
#pragma unroll
    for (int i = 0; i < CONVK; i++) {
        const int ts = t - (CONVK - 1) + i;
        if (ts >= 0) acc += vpre[(size_t)ts * HID + d] * w4[i];
    }
    v[idx] = siluf(acc);
}

// ---------------------------------------------------------------------------
// D1: chunk-local WY precompute, all fp32 (verified)
// ---------------------------------------------------------------------------
__global__ __launch_bounds__(256) void chunkloc_kernel(
    const float* __restrict__ q, const float* __restrict__ k, const float* __restrict__ v,
    const float* __restrict__ g, const float* __restrict__ beta,
    float* __restrict__ X1g, float* __restrict__ X2g,
    float* __restrict__ Mg, float* __restrict__ csg)
{
    __shared__ float KT[128 * 68];
    __shared__ float buf2[128 * 68];
    __shared__ float As[64 * 68];
    __shared__ float cs[64], sb[64], sbb[64];

    const int c = blockIdx.x, h = blockIdx.y;
    const int tid = threadIdx.x;
    const size_t rowbase = (size_t)(c * CH) * HID + h * DK;

    {
        const int i = tid >> 2, dq = tid & 3;
        const float* src = k + rowbase + (size_t)i * HID + dq * 32;
        for (int f = 0; f < 8; ++f) {
            float4 x = *(const float4*)(src + f * 4);
            int d = dq * 32 + f * 4;
            KT[(d + 0) * 68 + i] = x.x; KT[(d + 1) * 68 + i] = x.y;
            KT[(d + 2) * 68 + i] = x.z; KT[(d + 3) * 68 + i] = x.w;
        }
    }
    if (tid < 64) {
        float gv = g[(c * CH + tid) * NH + h];
        float bv = beta[(c * CH + tid) * NH + h];
        float csv = gv;
#pragma unroll
        for (int off = 1; off < 64; off <<= 1) {
            float n = __shfl_up(csv, off);
            if (tid >= off) csv += n;
        }
        cs[tid] = csv; sb[tid] = bv; sbb[tid] = bv * __expf(csv);
    }
    __syncthreads();

    {
        const int ti = tid & 15, tj = tid >> 4;
        const int j0 = ti * 4, i0 = tj * 4;
        float acc[4][4] = {{0}};
        for (int d = 0; d < 128; ++d) {
            float4 av = *(const float4*)&KT[d * 68 + i0];
            float4 bv = *(const float4*)&KT[d * 68 + j0];
            const float ap[4] = {av.x, av.y, av.z, av.w};
            const float bp[4] = {bv.x, bv.y, bv.z, bv.w};
#pragma unroll
            for (int r = 0; r < 4; ++r)
#pragma unroll
                for (int s = 0; s < 4; ++s) acc[r][s] += ap[r] * bp[s];
        }
#pragma unroll
        for (int r = 0; r < 4; ++r)
#pragma unroll
            for (int s = 0; s < 4; ++s) {
                int i = i0 + r, j = j0 + s;
                As[i * 68 + j] = (j < i) ? sb[i] * __expf(cs[i] - cs[j]) * acc[r][s] : 0.0f;
            }
    }

    float xc[64];
    const int col = tid;
    if (col >= 128) {
        const int dcol = col - 128;
#pragma unroll
        for (int i4 = 0; i4 < 16; ++i4) {
            float4 kq = *(const float4*)&KT[dcol * 68 + i4 * 4];
            xc[i4 * 4 + 0] = sbb[i4 * 4 + 0] * kq.x;
            xc[i4 * 4 + 1] = sbb[i4 * 4 + 1] * kq.y;
            xc[i4 * 4 + 2] = sbb[i4 * 4 + 2] * kq.z;
            xc[i4 * 4 + 3] = sbb[i4 * 4 + 3] * kq.w;
        }
    }

    {
        const int i = tid >> 2, cq = tid & 3;
        const float* src = v + (size_t)(c * CH + i) * HID + h * DV + cq * 32;
        for (int f = 0; f < 8; ++f)
            *(float4*)&buf2[i * 132 + cq * 32 + f * 4] = *(const float4*)(src + f * 4);
    }
    __syncthreads();

    if (col < 128) {
#pragma unroll
        for (int i = 0; i < 64; ++i) xc[i] = sb[i] * buf2[i * 132 + col];
    }

#pragma unroll
    for (int i = 1; i < 64; ++i) {
        float a = xc[i];
#pragma unroll
        for (int j4 = 0; j4 < (i + 3) / 4; ++j4) {
            float4 a4 = *(const float4*)&As[i * 68 + j4 * 4];
            a -= a4.x * xc[j4 * 4 + 0] + a4.y * xc[j4 * 4 + 1]
               + a4.z * xc[j4 * 4 + 2] + a4.w * xc[j4 * 4 + 3];
        }
        xc[i] = a;
    }

    {
        const size_t xbase = (size_t)(h * NC + c) * CH * 128;
        if (col < 128) {
            for (int i = 0; i < 64; ++i) X1g[xbase + (size_t)i * 128 + col] = xc[i];
        } else {
            for (int i = 0; i < 64; ++i) X2g[xbase + (size_t)i * 128 + (col - 128)] = xc[i];
        }
    }
    __syncthreads();

    {
        const int i = tid >> 2, dq = tid & 3;
        const float* qsrc = q + rowbase + (size_t)i * HID + dq * 32;
        for (int f = 0; f < 8; ++f) {
            float4 x = *(const float4*)(qsrc + f * 4);
            int d = dq * 32 + f * 4;
            buf2[(d + 0) * 68 + i] = x.x; buf2[(d + 1) * 68 + i] = x.y;
            buf2[(d + 2) * 68 + i] = x.z; buf2[(d + 3) * 68 + i] = x.w;
        }
    }
    __syncthreads();

    {
        const int ti = tid & 15, tj = tid >> 4;
        const int j0 = ti * 4, i0 = tj * 4;
        float acc[4][4] = {{0}};
        for (int d = 0; d < 128; ++d) {
            float4 qv = *(const float4*)&buf2[d * 68 + i0];
            float4 kv = *(const float4*)&KT[d * 68 + j0];
            const float ap[4] = {qv.x, qv.y, qv.z, qv.w};
            const float bp[4] = {kv.x, kv.y, kv.z, kv.w};
#pragma unroll
            for (int r = 0; r < 4; ++r)
#pragma unroll
                for (int s = 0; s < 4; ++s) acc[r][s] += ap[r] * bp[s];
        }
        const size_t mbase = (size_t)(h * NC + c) * CH * CH;
#pragma unroll
        for (int r = 0; r < 4; ++r)
#pragma unroll
            for (int s = 0; s < 4; ++s) {
                int i = i0 + r, j = j0 + s;
                Mg[mbase + (size_t)i * 64 + j] =
                    (j <= i) ? __expf(cs[i] - cs[j]) * acc[r][s] : 0.0f;
            }
    }
    if (tid < 64) csg[(size_t)(h * NC + c) * CH + tid] = cs[tid];
}

// ---------------------------------------------------------------------------
// D2: serial inter-chunk recurrence — software-pipelined.
// grid (NH, 8). Per chunk: 3 barriers; all staging prefetched into registers
// one chunk ahead (loads independent of S). U and o_qs fused in one phase.
// Ut in LDS holds exp(cs63-cs_i)*U_i so bufK stays raw k.
// ---------------------------------------------------------------------------
__global__ __launch_bounds__(256, 1) void state_kernel(
    const float* __restrict__ k, const float* __restrict__ q,
    float* __restrict__ X1g /* in: X1, out: U */,
    const float* __restrict__ X2g, const float* __restrict__ csg,
    float* __restrict__ o)
{
    __shared__ float bufX2[64 * 132];
    __shared__ float bufQ[64 * 132];
    __shared__ float bufK[64 * 132];
    __shared__ float St[16 * 132];
    __shared__ float Ut[16 * 68];
    __shared__ float scs[64];

    const int h = blockIdx.x, db = blockIdx.y;
    const int tid = threadIdx.x;
    const int cL = tid & 15, grp = tid >> 4;
    const int i0 = grp * 4;
    const int li = tid >> 2, lq = tid & 3;     // staging: row li, 32-col quarter lq

    for (int idx = tid; idx < 16 * 132; idx += 256) St[idx] = 0.0f;

    float rX2[32], rQ[32], rK[32], rX1[4], rcs = 0.0f;
    // prefetch chunk 0
    {
        const size_t xb0 = (size_t)(h * NC) * CH * 128;
#pragma unroll
        for (int f = 0; f < 8; ++f) {
            *(float4*)&rX2[f * 4] = *(const float4*)(X2g + xb0 + (size_t)li * 128 + lq * 32 + f * 4);
            *(float4*)&rQ[f * 4]  = *(const float4*)(q + (size_t)li * HID + h * DK + lq * 32 + f * 4);
            *(float4*)&rK[f * 4]  = *(const float4*)(k + (size_t)li * HID + h * DK + lq * 32 + f * 4);
        }
#pragma unroll
        for (int r = 0; r < 4; ++r)
            rX1[r] = X1g[xb0 + (size_t)(i0 + r) * 128 + db * 16 + cL];
        if (tid < 64) rcs = csg[(size_t)(h * NC) * CH + tid];
    }

    for (int c = 0; c < NC; ++c) {
        const size_t xb = (size_t)(h * NC + c) * CH * 128;
        // ---- stage: registers -> LDS ----
#pragma unroll
        for (int f = 0; f < 8; ++f) {
            *(float4*)&bufX2[li * 132 + lq * 32 + f * 4] = *(const float4*)&rX2[f * 4];
            *(float4*)&bufQ[li * 132 + lq * 32 + f * 4]  = *(const float4*)&rQ[f * 4];
            *(float4*)&bufK[li * 132 + lq * 32 + f * 4]  = *(const float4*)&rK[f * 4];
        }
        if (tid < 64) scs[tid] = rcs;
        float rX1c[4];
#pragma unroll
        for (int r = 0; r < 4; ++r) rX1c[r] = rX1[r];
        __syncthreads();

        // ---- prefetch chunk c+1 (overwrites regs; LDS already staged) ----
        {
            const int cn = (c + 1 < NC) ? c + 1 : c;
            const size_t xbn = (size_t)(h * NC + cn) * CH * 128;
#pragma unroll
            for (int f = 0; f < 8; ++f) {
                *(float4*)&rX2[f * 4] = *(const float4*)(X2g + xbn + (size_t)li * 128 + lq * 32 + f * 4);
                *(float4*)&rQ[f * 4]  = *(const float4*)(q + (size_t)(cn * CH + li) * HID + h * DK + lq * 32 + f * 4);
                *(float4*)&rK[f * 4]  = *(const float4*)(k + (size_t)(cn * CH + li) * HID + h * DK + lq * 32 + f * 4);
            }
#pragma unroll
            for (int r = 0; r < 4; ++r)
                rX1[r] = X1g[xbn + (size_t)(i0 + r) * 128 + db * 16 + cL];
            if (tid < 64) rcs = csg[(size_t)(h * NC + cn) * CH + tid];
        }

        // ---- fused U + o_qs phase (reads pre-update S) ----
        {
            float accU[4], accO[4];
#pragma unroll
            for (int r = 0; r < 4; ++r) { accU[r] = rX1c[r]; accO[r] = 0.0f; }
            for (int d4 = 0; d4 < 32; ++d4) {
                float4 s4 = *(const float4*)&St[cL * 132 + d4 * 4];
#pragma unroll
                for (int r = 0; r < 4; ++r) {
                    float4 x2 = *(const float4*)&bufX2[(i0 + r) * 132 + d4 * 4];
                    float4 qq = *(const float4*)&bufQ[(i0 + r) * 132 + d4 * 4];
                    accU[r] -= x2.x * s4.x + x2.y * s4.y + x2.z * s4.z + x2.w * s4.w;
                    accO[r] += qq.x * s4.x + qq.y * s4.y + qq.z * s4.z + qq.w * s4.w;
                }
            }
            const float cs63 = scs[63];
#pragma unroll
            for (int r = 0; r < 4; ++r) {
                const float u = accU[r];
                X1g[xb + (size_t)(i0 + r) * 128 + db * 16 + cL] = u;
                Ut[cL * 68 + i0 + r] = u * __expf(cs63 - scs[i0 + r]);
                o[(size_t)(c * CH + i0 + r) * HID + h * DV + db * 16 + cL] =
                    __expf(scs[i0 + r]) * accO[r];
            }
        }
        __syncthreads();

        // ---- S update: S = exp(cs63)*S + sum_i k_i * Ut'_i ----
        {
            const int dk0 = grp * 8;
            const float bC = __expf(scs[63]);
            float acc[8];
#pragma unroll
            for (int e = 0; e < 8; ++e) acc[e] = bC * St[cL * 132 + dk0 + e];
            for (int i4 = 0; i4 < 16; ++i4) {
                float4 u4 = *(const float4*)&Ut[cL * 68 + i4 * 4];
                const float uu[4] = {u4.x, u4.y, u4.z, u4.w};
#pragma unroll
                for (int s = 0; s < 4; ++s) {
                    const float* kr = &bufK[(i4 * 4 + s) * 132 + dk0];
#pragma unroll
                    for (int e = 0; e < 8; ++e) acc[e] += uu[s] * kr[e];
                }
            }
#pragma unroll
            for (int e = 0; e < 8; ++e) St[cL * 132 + dk0 + e] = acc[e];
        }
        __syncthreads();
    }
}

// ---------------------------------------------------------------------------
// D3: o = scale * (o + M U), all fp32 (verified)
// ---------------------------------------------------------------------------
__global__ __launch_bounds__(256) void outk_kernel(
    const float* __restrict__ Ug, const float* __restrict__ Mg,
    float* __restrict__ o)
{
    __shared__ float Msh[64 * 68];
    __shared__ float Ush[64 * 68];

    const int c = blockIdx.x, h = blockIdx.y;
    const int dvb = blockIdx.z * 64;
    const int tid = threadIdx.x;
    const size_t hc = (size_t)(h * NC + c);

    for (int e = 0; e < 16; ++e) {
        int idx = e * 256 + tid;
        Msh[(idx >> 6) * 68 + (idx & 63)] = Mg[hc * CH * CH + idx];
    }
    for (int e = 0; e < 16; ++e) {
        int idx = e * 256 + tid;
        int j = idx >> 6, cc = idx & 63;
        Ush[j * 68 + cc] = Ug[hc * CH * 128 + (size_t)j * 128 + dvb + cc];
    }
    __syncthreads();

    const int tx = tid & 15, ty = tid >> 4;
    const int c0 = tx * 4, i0 = ty * 4;
    float acc[4][4] = {{0}};
    for (int j4 = 0; j4 < 16; ++j4) {
        float uv[4][4];
#pragma unroll
        for (int s = 0; s < 4; ++s) {
            float4 u4 = *(const float4*)&Ush[(j4 * 4 + s) * 68 + c0];
            uv[s][0] = u4.x; uv[s][1] = u4.y; uv[s][2] = u4.z; uv[s][3] = u4.w;
        }
#pragma unroll
        for (int r = 0; r < 4; ++r) {
            float4 m4 = *(const float4*)&Msh[(i0 + r) * 68 + j4 * 4];
            const float mv[4] = {m4.x, m4.y, m4.z, m4.w};
#pragma unroll
            for (int s = 0; s < 4; ++s)
#pragma unroll
                for (int e = 0; e < 4; ++e) acc[r][e] += mv[s] * uv[s][e];
        }
    }
    const float scale = 0.08838834764831845f;
#pragma unroll
    for (int r = 0; r < 4; ++r) {
        float* op = &o[(size_t)(c * CH + i0 + r) * HID + h * DV + dvb + c0];
        float4 prev = *(const float4*)op;
        float4 ov = make_float4(scale * (prev.x + acc[r][0]),
                                scale * (prev.y + acc[r][1]),
                                scale * (prev.z + acc[r][2]),
                                scale * (prev.w + acc[r][3]));
        *(float4*)op = ov;
    }
}

// ---------------------------------------------------------------------------
// Gated RMSNorm: gsil bf16 in, onorm (hi,lo) bf16 out
// ---------------------------------------------------------------------------
__global__ __launch_bounds__(256) void normgate_kernel(const float* __restrict__ o,
                                                       const unsigned short* __restrict__ gsil,
                                                       const float* __restrict__ nw,
                                                       unsigned short* __restrict__ out_hi,
                                                       unsigned short* __restrict__ out_lo) {
    const int gw = (blockIdx.x * 256 + threadIdx.x) >> 6;
    const int lane = threadIdx.x & 63;
    if (gw >= T * NH) return;
    const int t = gw / NH, h = gw % NH;
    const size_t base = (size_t)t * HID + h * DV;
    const float a = o[base + lane];
    const float b = o[base + lane + 64];
    float ss = a * a + b * b;
    ss += __shfl_xor(ss, 1);  ss += __shfl_xor(ss, 2);  ss += __shfl_xor(ss, 4);
    ss += __shfl_xor(ss, 8);  ss += __shfl_xor(ss, 16); ss += __shfl_xor(ss, 32);
    const float r = rsqrtf(ss * (1.0f / 128.0f) + 1e-5f);
    float va = a * r * nw[lane]      * bf2f(gsil[base + lane]);
    float vb = b * r * nw[lane + 64] * bf2f(gsil[base + lane + 64]);
    unsigned short ha = f2bf(va), hb = f2bf(vb);
    out_hi[base + lane]      = ha;  out_lo[base + lane]      = f2bf(va - bf2f(ha));
    out_hi[base + lane + 64] = hb;  out_lo[base + lane + 64] = f2bf(vb - bf2f(hb));
}

// ---------------------------------------------------------------------------
extern "C" void kernel_launch(void* const* d_in, const int* in_sizes, int n_in,
                              void* d_out, int out_size, void* d_ws, size_t ws_size,
                              hipStream_t stream) {
    const float* hs      = (const float*)d_in[0];
    const float* Wq      = (const float*)d_in[1];
    const float* Wk      = (const float*)d_in[2];
    const float* Wv      = (const float*)d_in[3];
    const float* Wb      = (const float*)d_in[4];
    const float* Wa      = (const float*)d_in[5];
    const float* A_log   = (const float*)d_in[6];
    const float* dt_bias = (const float*)d_in[7];
    const float* Wg1     = (const float*)d_in[8];
    const float* Wg2     = (const float*)d_in[9];
    const float* Wgate   = (const float*)d_in[10];
    const float* norm_w  = (const float*)d_in[11];
    const float* Wo      = (const float*)d_in[12];

    float* ws = (float*)d_ws;
    float* q    = ws;
    float* kbuf = ws + 3145728;
    float* vpre = ws + 6291456;
    float* vbuf = ws + 9437184;
    unsigned short* gsil = (unsigned short*)(ws + 12582912);
    unsigned short* WTh = (unsigned short*)(ws + 14155776);
    unsigned short* WTl = (unsigned short*)(ws + 17694720);
    float* w1f  = ws + 21233664;
    unsigned short* wcv = (unsigned short*)(ws + 14155776);
    float* X1g  = ws + 14155776;
    float* X2g  = ws + 17301504;
    float* Mg   = ws + 20447232;
    unsigned short* WG2Th = (unsigned short*)(ws + 22044672);
    unsigned short* WG2Tl = (unsigned short*)(ws + 22634496);
    unsigned short* w1h   = (unsigned short*)(ws + 23224320);
    unsigned short* w1l   = (unsigned short*)(ws + 23420928);
    float* bgraw = ws + 23617536;
    float* beta  = ws + 23666688;
    float* g     = ws + 23691264;
    float* csg   = ws + 23715840;
    unsigned short* hsbh = (unsigned short*)(ws + 9437184);
    unsigned short* hsbl = (unsigned short*)(ws + 11010048);
    unsigned short* WoTh = (unsigned short*)(ws);
    unsigned short* WoTl = (unsigned short*)(ws + 1179648);
    unsigned short* onh  = (unsigned short*)(ws + 6291456);
    unsigned short* onl  = (unsigned short*)(ws + 7864320);

    const dim3 blk(256);
    const dim3 blkT(32, 8);

    // P0: split hs; transsplit projection batch A = [Wq|Wk|Wv]
    splitcast_kernel<<<3072, blk, 0, stream>>>(hs, hsbh, hsbl, (T * HID) / 4);
    transsplit_kernel<<<dim3(48, 48), blkT, 0, stream>>>(Wq, WTh,               WTl,               1536, 1536);
    transsplit_kernel<<<dim3(48, 48), blkT, 0, stream>>>(Wk, WTh + 1536 * 1536, WTl + 1536 * 1536, 1536, 1536);
    transsplit_kernel<<<dim3(48, 48), blkT, 0, stream>>>(Wv, WTh + 3072 * 1536, WTl + 3072 * 1536, 1536, 1536);

    // P1a: q|k|v projection (N=4608)
    mgemm<1><<<dim3(36, 16), blk, 0, stream>>>(hsbh, hsbl, WTh, WTl, 1536, 4608,
        nullptr, nullptr, q, kbuf, vpre, nullptr, nullptr, nullptr);

    // P1b: gate|w1|bg projection (N=1792), reusing the WT buffer
    transsplit_kernel<<<dim3(48, 48), blkT, 0, stream>>>(Wgate, WTh,               WTl,               1536, 1536);
    transsplit_kernel<<<dim3(6, 48),  blkT, 0, stream>>>(Wg1,   WTh + 1536 * 1536, WTl + 1536 * 1536, 1536, 192);
    transsplit_kernel<<<dim3(1, 48),  blkT, 0, stream>>>(Wb,    WTh + 1728 * 1536, WTl + 1728 * 1536, 1536, 12);
    transsplit_kernel<<<dim3(1, 48),  blkT, 0, stream>>>(Wa,    WTh + 1740 * 1536, WTl + 1740 * 1536, 1536, 12);
    mgemm<2><<<dim3(14, 16), blk, 0, stream>>>(hsbh, hsbl, WTh, WTl, 1536, 1792,
        nullptr, nullptr, nullptr, nullptr, nullptr, gsil, w1f, bgraw);
    bg2_kernel<<<192, blk, 0, stream>>>(bgraw, A_log, dt_bias, beta, g);
    splitcast_kernel<<<384, blk, 0, stream>>>(w1f, w1h, w1l, (2048 * 192) / 4);

    // P2: conv weights GEMM (bf16 out) + conv
    transsplit_kernel<<<dim3(192, 6), blkT, 0, stream>>>(Wg2, WG2Th, WG2Tl, 192, 6144);
    mgemm<3><<<dim3(48, 16), blk, 0, stream>>>(w1h, w1l, WG2Th, WG2Tl, 192, 6144,
        nullptr, wcv, nullptr, nullptr, nullptr, nullptr, nullptr, nullptr);
    conv_kernel<<<(T * HID) / 256, blk, 0, stream>>>(vpre, wcv, vbuf);

    // P3: chunked delta rule (fp32)
    chunkloc_kernel<<<dim3(NC, NH), blk, 0, stream>>>(q, kbuf, vbuf, g, beta,
                                                      X1g, X2g, Mg, csg);
    state_kernel<<<dim3(NH, 8), blk, 0, stream>>>(kbuf, q, X1g, X2g, csg, vbuf);
    transsplit_kernel<<<dim3(48, 48), blkT, 0, stream>>>(Wo, WoTh, WoTl, 1536, 1536);
    outk_kernel<<<dim3(NC, NH, 2), blk, 0, stream>>>(X1g, Mg, vbuf);

    // P4: norm + output GEMM
    normgate_kernel<<<6144, blk, 0, stream>>>(vbuf, gsil, norm_w, onh, onl);
    mgemm<0><<<dim3(12, 16), blk, 0, stream>>>(onh, onl, WoTh, WoTl, 1536, 1536,
        (float*)d_out, nullptr, nullptr, nullptr, nullptr, nullptr, nullptr, nullptr);
}

// Round 7
// 819.395 us; speedup vs baseline: 1.2948x; 1.2948x over previous
//
#include <hip/hip_runtime.h>
#include <hip/hip_bf16.h>
#include <math.h>

#define T     2048
#define HID   1536
#define NH    12
#define DK    128
#define DV    128
#define CONVK 4
#define CH    64
#define NC    32

typedef __attribute__((ext_vector_type(8))) short bf16x8;
typedef __attribute__((ext_vector_type(4))) float floatx4;

__device__ __forceinline__ float siluf(float x) {
    return x / (1.0f + __expf(-x));
}
__device__ __forceinline__ unsigned short f2bf(float f) {
    union { __hip_bfloat16 b; unsigned short u; } cv;
    cv.b = __float2bfloat16(f);
    return cv.u;
}
__device__ __forceinline__ float bf2f(unsigned short u) {
    union { unsigned int u; float f; } cv;
    cv.u = ((unsigned int)u) << 16;
    return cv.f;
}
__device__ __forceinline__ void gl_lds16(const void* g, void* l) {
    __builtin_amdgcn_global_load_lds(
        (const __attribute__((address_space(1))) void*)g,
        (__attribute__((address_space(3))) void*)l, 16, 0, 0);
}

// ---------------------------------------------------------------------------
// split fp32 -> (hi, lo) bf16 pair, vectorized x4
// ---------------------------------------------------------------------------
__global__ __launch_bounds__(256) void splitcast_kernel(const float* __restrict__ s,
                                                        unsigned short* __restrict__ hi,
                                                        unsigned short* __restrict__ lo,
                                                        int n4) {
    int i = blockIdx.x * 256 + threadIdx.x;
    if (i >= n4) return;
    float4 x = ((const float4*)s)[i];
    ushort4 h, l;
    h.x = f2bf(x.x); l.x = f2bf(x.x - bf2f(h.x));
    h.y = f2bf(x.y); l.y = f2bf(x.y - bf2f(h.y));
    h.z = f2bf(x.z); l.z = f2bf(x.z - bf2f(h.z));
    h.w = f2bf(x.w); l.w = f2bf(x.w - bf2f(h.w));
    ((ushort4*)hi)[i] = h;
    ((ushort4*)lo)[i] = l;
}

// ---------------------------------------------------------------------------
// transpose + split: src (K x N fp32) -> hi/lo (N x K bf16). K%32==0.
// ---------------------------------------------------------------------------
__global__ __launch_bounds__(256) void transsplit_kernel(const float* __restrict__ src,
                                                         unsigned short* __restrict__ hi,
                                                         unsigned short* __restrict__ lo,
                                                         int K, int N) {
    __shared__ float tile[32][33];
    const int k0 = blockIdx.y * 32, n0 = blockIdx.x * 32;
    const int tx = threadIdx.x, ty = threadIdx.y;
#pragma unroll
    for (int r = 0; r < 4; ++r) {
        int kk = k0 + ty + 8 * r, nn = n0 + tx;
        tile[ty + 8 * r][tx] = (nn < N) ? src[(size_t)kk * N + nn] : 0.0f;
    }
    __syncthreads();
#pragma unroll
    for (int r = 0; r < 4; ++r) {
        int nn = n0 + ty + 8 * r, kk = k0 + tx;
        if (nn < N) {
            float x = tile[tx][ty + 8 * r];
            unsigned short h = f2bf(x);
            hi[(size_t)nn * K + kk] = h;
            lo[(size_t)nn * K + kk] = f2bf(x - bf2f(h));
        }
    }
}

// ---------------------------------------------------------------------------
// Split-bf16 MFMA GEMM (effectively fp32): C = (Ah+Al)(Bh+Bl)^T, lo*lo dropped.
// ---------------------------------------------------------------------------
template<int EPI>
__global__ __launch_bounds__(256)
void mgemm(const unsigned short* __restrict__ Ah, const unsigned short* __restrict__ Al,
           const unsigned short* __restrict__ Bh, const unsigned short* __restrict__ Bl,
           int K, int N, float* __restrict__ C, unsigned short* __restrict__ Cb,
           float* __restrict__ qf, float* __restrict__ kf, float* __restrict__ vf,
           unsigned short* __restrict__ gsilb, float* __restrict__ w1f,
           float* __restrict__ bgraw)
{
    __shared__ unsigned short AsH[4096], AsL[4096], BsH[4096], BsL[4096];
    const int tid = threadIdx.x;
    const int wave = tid >> 6, lane = tid & 63;
    const int wr = wave >> 1, wc = wave & 1;
    const int lm = lane & 15, lq = lane >> 4;
    const int rowBase = blockIdx.y * 128, colBase = blockIdx.x * 128;

    floatx4 acc[4][4];
#pragma unroll
    for (int i = 0; i < 4; ++i)
#pragma unroll
        for (int j = 0; j < 4; ++j) acc[i][j] = (floatx4){0.f, 0.f, 0.f, 0.f};

    const int mt0 = wave * 2, mt1 = wave * 2 + 1;
    const size_t aOff0 = (size_t)(rowBase + mt0 * 16 + lm) * K + lq * 8;
    const size_t aOff1 = (size_t)(rowBase + mt1 * 16 + lm) * K + lq * 8;
    const size_t bOff0 = (size_t)(colBase + mt0 * 16 + lm) * K + lq * 8;
    const size_t bOff1 = (size_t)(colBase + mt1 * 16 + lm) * K + lq * 8;

    for (int k0 = 0; k0 < K; k0 += 32) {
        gl_lds16(Ah + aOff0 + k0, &AsH[mt0 * 512]);
        gl_lds16(Ah + aOff1 + k0, &AsH[mt1 * 512]);
        gl_lds16(Al + aOff0 + k0, &AsL[mt0 * 512]);
        gl_lds16(Al + aOff1 + k0, &AsL[mt1 * 512]);
        gl_lds16(Bh + bOff0 + k0, &BsH[mt0 * 512]);
        gl_lds16(Bh + bOff1 + k0, &BsH[mt1 * 512]);
        gl_lds16(Bl + bOff0 + k0, &BsL[mt0 * 512]);
        gl_lds16(Bl + bOff1 + k0, &BsL[mt1 * 512]);
        __syncthreads();
        bf16x8 ah[4], al[4], bh[4], bl[4];
#pragma unroll
        for (int i = 0; i < 4; ++i) {
            ah[i] = *(const bf16x8*)&AsH[(wr * 4 + i) * 512 + lane * 8];
            al[i] = *(const bf16x8*)&AsL[(wr * 4 + i) * 512 + lane * 8];
            bh[i] = *(const bf16x8*)&BsH[(wc * 4 + i) * 512 + lane * 8];
            bl[i] = *(const bf16x8*)&BsL[(wc * 4 + i) * 512 + lane * 8];
        }
#pragma unroll
        for (int mi = 0; mi < 4; ++mi)
#pragma unroll
            for (int ni = 0; ni < 4; ++ni) {
                acc[mi][ni] = __builtin_amdgcn_mfma_f32_16x16x32_bf16(
                    ah[mi], bh[ni], acc[mi][ni], 0, 0, 0);
                acc[mi][ni] = __builtin_amdgcn_mfma_f32_16x16x32_bf16(
                    ah[mi], bl[ni], acc[mi][ni], 0, 0, 0);
                acc[mi][ni] = __builtin_amdgcn_mfma_f32_16x16x32_bf16(
                    al[mi], bh[ni], acc[mi][ni], 0, 0, 0);
            }
        __syncthreads();
    }

#pragma unroll
    for (int mi = 0; mi < 4; ++mi)
#pragma unroll
        for (int ni = 0; ni < 4; ++ni) {
            const int col = colBase + wc * 64 + ni * 16 + lm;
#pragma unroll
            for (int r = 0; r < 4; ++r) {
                const int row = rowBase + wr * 64 + mi * 16 + lq * 4 + r;
                const float x = acc[mi][ni][r];
                if (EPI == 0) {
                    C[(size_t)row * N + col] = x;
                } else if (EPI == 3) {
                    Cb[(size_t)row * N + col] = f2bf(x);
                } else if (EPI == 1) {
                    if (col < 1536)       qf[(size_t)row * 1536 + col] = siluf(x);
                    else if (col < 3072)  kf[(size_t)row * 1536 + col - 1536] = siluf(x);
                    else                  vf[(size_t)row * 1536 + col - 3072] = x;
                } else {  // EPI == 2
                    if (col < 1536)       gsilb[(size_t)row * 1536 + col] = f2bf(siluf(x));
                    else if (col < 1728)  w1f[(size_t)row * 192 + col - 1536] = siluf(x);
                    else if (col < 1752)  bgraw[(size_t)row * 24 + col - 1728] = x;
                }
            }
        }
}

// ---------------------------------------------------------------------------
__global__ __launch_bounds__(256) void bg2_kernel(const float* __restrict__ bgraw,
                                                  const float* __restrict__ A_log,
                                                  const float* __restrict__ dt_bias,
                                                  float* __restrict__ beta,
                                                  float* __restrict__ g) {
    int idx = blockIdx.x * 256 + threadIdx.x;
    if (idx >= T * 24) return;
    int t = idx / 24, c = idx % 24;
    float x = bgraw[idx];
    if (c < 12) {
        beta[t * NH + c] = 1.0f / (1.0f + __expf(-x));
    } else {
        int h = c - 12;
        float y = x + dt_bias[h];
        float sp = (y > 20.0f) ? y : log1pf(__expf(y));
        g[t * NH + h] = -__expf(A_log[h]) * sp;
    }
}

// ---------------------------------------------------------------------------
__global__ __launch_bounds__(256) void conv_kernel(const float* __restrict__ vpre,
                                                   const unsigned short* __restrict__ w,
                                                   float* __restrict__ v) {
    const int idx = blockIdx.x * 256 + threadIdx.x;
    if (idx >= T * HID) return;
    const int t = idx / HID, d = idx % HID;
    const ushort4 wv = *(const ushort4*)(w + (size_t)t * (HID * CONVK) + d * 4);
    const float w4[4] = { bf2f(wv.x), bf2f(wv.y), bf2f(wv.z), bf2f(wv.w) };
    float acc = 0.0f;
#pragma unroll
    for (int i = 0; i < CONVK; i++) {
        const int ts = t - (CONVK - 1) + i;
        if (ts >= 0) acc += vpre[(size_t)ts * HID + d] * w4[i];
    }
    v[idx] = siluf(acc);
}

// ---------------------------------------------------------------------------
// D1: chunk-local WY precompute, all fp32 (verified)
// ---------------------------------------------------------------------------
__global__ __launch_bounds__(256) void chunkloc_kernel(
    const float* __restrict__ q, const float* __restrict__ k, const float* __restrict__ v,
    const float* __restrict__ g, const float* __restrict__ beta,
    float* __restrict__ X1g, float* __restrict__ X2g,
    float* __restrict__ Mg, float* __restrict__ csg)
{
    __shared__ float KT[128 * 68];
    __shared__ float buf2[128 * 68];
    __shared__ float As[64 * 68];
    __shared__ float cs[64], sb[64], sbb[64];

    const int c = blockIdx.x, h = blockIdx.y;
    const int tid = threadIdx.x;
    const size_t rowbase = (size_t)(c * CH) * HID + h * DK;

    {
        const int i = tid >> 2, dq = tid & 3;
        const float* src = k + rowbase + (size_t)i * HID + dq * 32;
        for (int f = 0; f < 8; ++f) {
            float4 x = *(const float4*)(src + f * 4);
            int d = dq * 32 + f * 4;
            KT[(d + 0) * 68 + i] = x.x; KT[(d + 1) * 68 + i] = x.y;
            KT[(d + 2) * 68 + i] = x.z; KT[(d + 3) * 68 + i] = x.w;
        }
    }
    if (tid < 64) {
        float gv = g[(c * CH + tid) * NH + h];
        float bv = beta[(c * CH + tid) * NH + h];
        float csv = gv;
#pragma unroll
        for (int off = 1; off < 64; off <<= 1) {
            float n = __shfl_up(csv, off);
            if (tid >= off) csv += n;
        }
        cs[tid] = csv; sb[tid] = bv; sbb[tid] = bv * __expf(csv);
    }
    __syncthreads();

    {
        const int ti = tid & 15, tj = tid >> 4;
        const int j0 = ti * 4, i0 = tj * 4;
        float acc[4][4] = {{0}};
        for (int d = 0; d < 128; ++d) {
            float4 av = *(const float4*)&KT[d * 68 + i0];
            float4 bv = *(const float4*)&KT[d * 68 + j0];
            const float ap[4] = {av.x, av.y, av.z, av.w};
            const float bp[4] = {bv.x, bv.y, bv.z, bv.w};
#pragma unroll
            for (int r = 0; r < 4; ++r)
#pragma unroll
                for (int s = 0; s < 4; ++s) acc[r][s] += ap[r] * bp[s];
        }
#pragma unroll
        for (int r = 0; r < 4; ++r)
#pragma unroll
            for (int s = 0; s < 4; ++s) {
                int i = i0 + r, j = j0 + s;
                As[i * 68 + j] = (j < i) ? sb[i] * __expf(cs[i] - cs[j]) * acc[r][s] : 0.0f;
            }
    }

    float xc[64];
    const int col = tid;
    if (col >= 128) {
        const int dcol = col - 128;
#pragma unroll
        for (int i4 = 0; i4 < 16; ++i4) {
            float4 kq = *(const float4*)&KT[dcol * 68 + i4 * 4];
            xc[i4 * 4 + 0] = sbb[i4 * 4 + 0] * kq.x;
            xc[i4 * 4 + 1] = sbb[i4 * 4 + 1] * kq.y;
            xc[i4 * 4 + 2] = sbb[i4 * 4 + 2] * kq.z;
            xc[i4 * 4 + 3] = sbb[i4 * 4 + 3] * kq.w;
        }
    }

    {
        const int i = tid >> 2, cq = tid & 3;
        const float* src = v + (size_t)(c * CH + i) * HID + h * DV + cq * 32;
        for (int f = 0; f < 8; ++f)
            *(float4*)&buf2[i * 132 + cq * 32 + f * 4] = *(const float4*)(src + f * 4);
    }
    __syncthreads();

    if (col < 128) {
#pragma unroll
        for (int i = 0; i < 64; ++i) xc[i] = sb[i] * buf2[i * 132 + col];
    }

#pragma unroll
    for (int i = 1; i < 64; ++i) {
        float a = xc[i];
#pragma unroll
        for (int j4 = 0; j4 < (i + 3) / 4; ++j4) {
            float4 a4 = *(const float4*)&As[i * 68 + j4 * 4];
            a -= a4.x * xc[j4 * 4 + 0] + a4.y * xc[j4 * 4 + 1]
               + a4.z * xc[j4 * 4 + 2] + a4.w * xc[j4 * 4 + 3];
        }
        xc[i] = a;
    }

    {
        const size_t xbase = (size_t)(h * NC + c) * CH * 128;
        if (col < 128) {
            for (int i = 0; i < 64; ++i) X1g[xbase + (size_t)i * 128 + col] = xc[i];
        } else {
            for (int i = 0; i < 64; ++i) X2g[xbase + (size_t)i * 128 + (col - 128)] = xc[i];
        }
    }
    __syncthreads();

    {
        const int i = tid >> 2, dq = tid & 3;
        const float* qsrc = q + rowbase + (size_t)i * HID + dq * 32;
        for (int f = 0; f < 8; ++f) {
            float4 x = *(const float4*)(qsrc + f * 4);
            int d = dq * 32 + f * 4;
            buf2[(d + 0) * 68 + i] = x.x; buf2[(d + 1) * 68 + i] = x.y;
            buf2[(d + 2) * 68 + i] = x.z; buf2[(d + 3) * 68 + i] = x.w;
        }
    }
    __syncthreads();

    {
        const int ti = tid & 15, tj = tid >> 4;
        const int j0 = ti * 4, i0 = tj * 4;
        float acc[4][4] = {{0}};
        for (int d = 0; d < 128; ++d) {
            float4 qv = *(const float4*)&buf2[d * 68 + i0];
            float4 kv = *(const float4*)&KT[d * 68 + j0];
            const float ap[4] = {qv.x, qv.y, qv.z, qv.w};
            const float bp[4] = {kv.x, kv.y, kv.z, kv.w};
#pragma unroll
            for (int r = 0; r < 4; ++r)
#pragma unroll
                for (int s = 0; s < 4; ++s) acc[r][s] += ap[r] * bp[s];
        }
        const size_t mbase = (size_t)(h * NC + c) * CH * CH;
#pragma unroll
        for (int r = 0; r < 4; ++r)
#pragma unroll
            for (int s = 0; s < 4; ++s) {
                int i = i0 + r, j = j0 + s;
                Mg[mbase + (size_t)i * 64 + j] =
                    (j <= i) ? __expf(cs[i] - cs[j]) * acc[r][s] : 0.0f;
            }
    }
    if (tid < 64) csg[(size_t)(h * NC + c) * CH + tid] = cs[tid];
}

// ---------------------------------------------------------------------------
// D2: serial inter-chunk recurrence — split-bf16 MFMA version.
// grid (NH, 8): head x dv-slice(16). 3 barriers/chunk.
// Master S fp32 in LDS (St, [dv][dk]); per chunk S is read as hi/lo bf16
// (SB, B-operand layout) and updated via MFMA:
//   phase1: stage (-X2) and Q as A-operand hi/lo [i][dk]; K raw transposed
//           hi/lo [dk][i]; cs.
//   phase2: U = X1 + (-X2)·S ; o1 = exp(cs_i)·(Q·S)  -> X1g, o, UB(hi/lo,
//           scaled by exp(cs63-cs_i), layout [dv][i])
//   phase3: S = exp(cs63)·S + K^T·U'  (MFMA, acc init from fp32 St)
// ---------------------------------------------------------------------------
__global__ __launch_bounds__(256, 1) void state_kernel(
    const float* __restrict__ k, const float* __restrict__ q,
    float* __restrict__ X1g /* in: X1, out: U */,
    const float* __restrict__ X2g, const float* __restrict__ csg,
    float* __restrict__ o)
{
    __shared__ unsigned short X2Ah[64 * 136], X2Al[64 * 136];  // -X2, A-op [i][dk]
    __shared__ unsigned short QAh [64 * 136], QAl [64 * 136];  //  Q,  A-op [i][dk]
    __shared__ unsigned short KTh [128 * 72], KTl [128 * 72];  //  K^T, A-op [dk][i]
    __shared__ unsigned short SBh [16 * 136], SBl [16 * 136];  //  S^T, B-op [dv][dk]
    __shared__ unsigned short UBh [16 * 72],  UBl [16 * 72];   //  U'^T, B-op [dv][i]
    __shared__ float St[16 * 132];                             //  S^T fp32 master
    __shared__ float scs[64];

    const int h = blockIdx.x, db = blockIdx.y;
    const int tid = threadIdx.x;
    const int wave = tid >> 6, lane = tid & 63;
    const int lm = lane & 15, lq = lane >> 4;    // MFMA fragment indices
    const int li = tid >> 2, lq4 = tid & 3;      // staging indices

    for (int idx = tid; idx < 16 * 132; idx += 256) St[idx] = 0.0f;
    for (int idx = tid; idx < 16 * 136; idx += 256) { SBh[idx] = 0; SBl[idx] = 0; }
    __syncthreads();

    for (int c = 0; c < NC; ++c) {
        const size_t hc = (size_t)(h * NC + c);
        const size_t xb = hc * CH * 128;

        // ---- phase 1: stage -X2, Q (A-layout), K^T, cs ----
        {
            if (tid < 64) scs[tid] = csg[hc * CH + tid];
            const float* x2p = X2g + xb + (size_t)li * 128 + lq4 * 32;
            const float* qp  = q + (size_t)(c * CH + li) * HID + h * DK + lq4 * 32;
            const float* kp  = k + (size_t)(c * CH + li) * HID + h * DK + lq4 * 32;
#pragma unroll
            for (int f = 0; f < 8; ++f) {
                float4 x2 = *(const float4*)(x2p + f * 4);
                float4 qq = *(const float4*)(qp + f * 4);
                float4 kk = *(const float4*)(kp + f * 4);
                const int dbase = lq4 * 32 + f * 4;
                // -X2 split
                {
                    const float v0 = -x2.x, v1 = -x2.y, v2 = -x2.z, v3 = -x2.w;
                    ushort4 hh, ll;
                    hh.x = f2bf(v0); ll.x = f2bf(v0 - bf2f(hh.x));
                    hh.y = f2bf(v1); ll.y = f2bf(v1 - bf2f(hh.y));
                    hh.z = f2bf(v2); ll.z = f2bf(v2 - bf2f(hh.z));
                    hh.w = f2bf(v3); ll.w = f2bf(v3 - bf2f(hh.w));
                    *(ushort4*)&X2Ah[li * 136 + dbase] = hh;
                    *(ushort4*)&X2Al[li * 136 + dbase] = ll;
                }
                // Q split
                {
                    ushort4 hh, ll;
                    hh.x = f2bf(qq.x); ll.x = f2bf(qq.x - bf2f(hh.x));
                    hh.y = f2bf(qq.y); ll.y = f2bf(qq.y - bf2f(hh.y));
                    hh.z = f2bf(qq.z); ll.z = f2bf(qq.z - bf2f(hh.z));
                    hh.w = f2bf(qq.w); ll.w = f2bf(qq.w - bf2f(hh.w));
                    *(ushort4*)&QAh[li * 136 + dbase] = hh;
                    *(ushort4*)&QAl[li * 136 + dbase] = ll;
                }
                // K transposed split (raw k; decay is carried by U')
                {
                    const float kv[4] = {kk.x, kk.y, kk.z, kk.w};
#pragma unroll
                    for (int e = 0; e < 4; ++e) {
                        unsigned short hh = f2bf(kv[e]);
                        KTh[(dbase + e) * 72 + li] = hh;
                        KTl[(dbase + e) * 72 + li] = f2bf(kv[e] - bf2f(hh));
                    }
                }
            }
        }
        __syncthreads();

        // ---- phase 2: U + o1 via MFMA ----
        {
            const int mw = wave;            // M-tile: rows i = mw*16 .. +15
            floatx4 accU, accO = (floatx4){0.f, 0.f, 0.f, 0.f};
            {
                float x1r[4];
#pragma unroll
                for (int r = 0; r < 4; ++r)
                    x1r[r] = X1g[xb + (size_t)(mw * 16 + lq * 4 + r) * 128 + db * 16 + lm];
                accU = (floatx4){x1r[0], x1r[1], x1r[2], x1r[3]};
            }
#pragma unroll
            for (int ks = 0; ks < 4; ++ks) {
                bf16x8 xh = *(const bf16x8*)&X2Ah[(mw * 16 + lm) * 136 + ks * 32 + lq * 8];
                bf16x8 xl = *(const bf16x8*)&X2Al[(mw * 16 + lm) * 136 + ks * 32 + lq * 8];
                bf16x8 qh = *(const bf16x8*)&QAh [(mw * 16 + lm) * 136 + ks * 32 + lq * 8];
                bf16x8 ql = *(const bf16x8*)&QAl [(mw * 16 + lm) * 136 + ks * 32 + lq * 8];
                bf16x8 sh = *(const bf16x8*)&SBh[lm * 136 + ks * 32 + lq * 8];
                bf16x8 sl = *(const bf16x8*)&SBl[lm * 136 + ks * 32 + lq * 8];
                accU = __builtin_amdgcn_mfma_f32_16x16x32_bf16(xh, sh, accU, 0, 0, 0);
                accU = __builtin_amdgcn_mfma_f32_16x16x32_bf16(xh, sl, accU, 0, 0, 0);
                accU = __builtin_amdgcn_mfma_f32_16x16x32_bf16(xl, sh, accU, 0, 0, 0);
                accO = __builtin_amdgcn_mfma_f32_16x16x32_bf16(qh, sh, accO, 0, 0, 0);
                accO = __builtin_amdgcn_mfma_f32_16x16x32_bf16(qh, sl, accO, 0, 0, 0);
                accO = __builtin_amdgcn_mfma_f32_16x16x32_bf16(ql, sh, accO, 0, 0, 0);
            }
            const float cs63 = scs[63];
#pragma unroll
            for (int r = 0; r < 4; ++r) {
                const int row = mw * 16 + lq * 4 + r;
                const float u = accU[r];
                X1g[xb + (size_t)row * 128 + db * 16 + lm] = u;
                const float up = u * __expf(cs63 - scs[row]);
                unsigned short uh = f2bf(up);
                UBh[lm * 72 + row] = uh;
                UBl[lm * 72 + row] = f2bf(up - bf2f(uh));
                o[(size_t)(c * CH + row) * HID + h * DV + db * 16 + lm] =
                    __expf(scs[row]) * accO[r];
            }
        }
        __syncthreads();

        // ---- phase 3: S = exp(cs63)*S + K^T U' via MFMA ----
        {
            const float bC = __expf(scs[63]);
#pragma unroll
            for (int mt2 = 0; mt2 < 2; ++mt2) {
                const int mt = wave * 2 + mt2;   // M-tile over dk: rows mt*16..+15
                floatx4 acc;
#pragma unroll
                for (int r = 0; r < 4; ++r)
                    acc[r] = bC * St[lm * 132 + mt * 16 + lq * 4 + r];
#pragma unroll
                for (int ks = 0; ks < 2; ++ks) {
                    bf16x8 ah = *(const bf16x8*)&KTh[(mt * 16 + lm) * 72 + ks * 32 + lq * 8];
                    bf16x8 al = *(const bf16x8*)&KTl[(mt * 16 + lm) * 72 + ks * 32 + lq * 8];
                    bf16x8 bh = *(const bf16x8*)&UBh[lm * 72 + ks * 32 + lq * 8];
                    bf16x8 bl = *(const bf16x8*)&UBl[lm * 72 + ks * 32 + lq * 8];
                    acc = __builtin_amdgcn_mfma_f32_16x16x32_bf16(ah, bh, acc, 0, 0, 0);
                    acc = __builtin_amdgcn_mfma_f32_16x16x32_bf16(ah, bl, acc, 0, 0, 0);
                    acc = __builtin_amdgcn_mfma_f32_16x16x32_bf16(al, bh, acc, 0, 0, 0);
                }
#pragma unroll
                for (int r = 0; r < 4; ++r) {
                    const int dk = mt * 16 + lq * 4 + r;
                    const float sv = acc[r];
                    St[lm * 132 + dk] = sv;
                    unsigned short sh = f2bf(sv);
                    SBh[lm * 136 + dk] = sh;
                    SBl[lm * 136 + dk] = f2bf(sv - bf2f(sh));
                }
            }
        }
        __syncthreads();
    }
}

// ---------------------------------------------------------------------------
// D3: o = scale * (o + M U), all fp32 (verified)
// ---------------------------------------------------------------------------
__global__ __launch_bounds__(256) void outk_kernel(
    const float* __restrict__ Ug, const float* __restrict__ Mg,
    float* __restrict__ o)
{
    __shared__ float Msh[64 * 68];
    __shared__ float Ush[64 * 68];

    const int c = blockIdx.x, h = blockIdx.y;
    const int dvb = blockIdx.z * 64;
    const int tid = threadIdx.x;
    const size_t hc = (size_t)(h * NC + c);

    for (int e = 0; e < 16; ++e) {
        int idx = e * 256 + tid;
        Msh[(idx >> 6) * 68 + (idx & 63)] = Mg[hc * CH * CH + idx];
    }
    for (int e = 0; e < 16; ++e) {
        int idx = e * 256 + tid;
        int j = idx >> 6, cc = idx & 63;
        Ush[j * 68 + cc] = Ug[hc * CH * 128 + (size_t)j * 128 + dvb + cc];
    }
    __syncthreads();

    const int tx = tid & 15, ty = tid >> 4;
    const int c0 = tx * 4, i0 = ty * 4;
    float acc[4][4] = {{0}};
    for (int j4 = 0; j4 < 16; ++j4) {
        float uv[4][4];
#pragma unroll
        for (int s = 0; s < 4; ++s) {
            float4 u4 = *(const float4*)&Ush[(j4 * 4 + s) * 68 + c0];
            uv[s][0] = u4.x; uv[s][1] = u4.y; uv[s][2] = u4.z; uv[s][3] = u4.w;
        }
#pragma unroll
        for (int r = 0; r < 4; ++r) {
            float4 m4 = *(const float4*)&Msh[(i0 + r) * 68 + j4 * 4];
            const float mv[4] = {m4.x, m4.y, m4.z, m4.w};
#pragma unroll
            for (int s = 0; s < 4; ++s)
#pragma unroll
                for (int e = 0; e < 4; ++e) acc[r][e] += mv[s] * uv[s][e];
        }
    }
    const float scale = 0.08838834764831845f;
#pragma unroll
    for (int r = 0; r < 4; ++r) {
        float* op = &o[(size_t)(c * CH + i0 + r) * HID + h * DV + dvb + c0];
        float4 prev = *(const float4*)op;
        float4 ov = make_float4(scale * (prev.x + acc[r][0]),
                                scale * (prev.y + acc[r][1]),
                                scale * (prev.z + acc[r][2]),
                                scale * (prev.w + acc[r][3]));
        *(float4*)op = ov;
    }
}

// ---------------------------------------------------------------------------
// Gated RMSNorm: gsil bf16 in, onorm (hi,lo) bf16 out
// ---------------------------------------------------------------------------
__global__ __launch_bounds__(256) void normgate_kernel(const float* __restrict__ o,
                                                       const unsigned short* __restrict__ gsil,
                                                       const float* __restrict__ nw,
                                                       unsigned short* __restrict__ out_hi,
                                                       unsigned short* __restrict__ out_lo) {
    const int gw = (blockIdx.x * 256 + threadIdx.x) >> 6;
    const int lane = threadIdx.x & 63;
    if (gw >= T * NH) return;
    const int t = gw / NH, h = gw % NH;
    const size_t base = (size_t)t * HID + h * DV;
    const float a = o[base + lane];
    const float b = o[base + lane + 64];
    float ss = a * a + b * b;
    ss += __shfl_xor(ss, 1);  ss += __shfl_xor(ss, 2);  ss += __shfl_xor(ss, 4);
    ss += __shfl_xor(ss, 8);  ss += __shfl_xor(ss, 16); ss += __shfl_xor(ss, 32);
    const float r = rsqrtf(ss * (1.0f / 128.0f) + 1e-5f);
    float va = a * r * nw[lane]      * bf2f(gsil[base + lane]);
    float vb = b * r * nw[lane + 64] * bf2f(gsil[base + lane + 64]);
    unsigned short ha = f2bf(va), hb = f2bf(vb);
    out_hi[base + lane]      = ha;  out_lo[base + lane]      = f2bf(va - bf2f(ha));
    out_hi[base + lane + 64] = hb;  out_lo[base + lane + 64] = f2bf(vb - bf2f(hb));
}

// ---------------------------------------------------------------------------
extern "C" void kernel_launch(void* const* d_in, const int* in_sizes, int n_in,
                              void* d_out, int out_size, void* d_ws, size_t ws_size,
                              hipStream_t stream) {
    const float* hs      = (const float*)d_in[0];
    const float* Wq      = (const float*)d_in[1];
    const float* Wk      = (const float*)d_in[2];
    const float* Wv      = (const float*)d_in[3];
    const float* Wb      = (const float*)d_in[4];
    const float* Wa      = (const float*)d_in[5];
    const float* A_log   = (const float*)d_in[6];
    const float* dt_bias = (const float*)d_in[7];
    const float* Wg1     = (const float*)d_in[8];
    const float* Wg2     = (const float*)d_in[9];
    const float* Wgate   = (const float*)d_in[10];
    const float* norm_w  = (const float*)d_in[11];
    const float* Wo      = (const float*)d_in[12];

    float* ws = (float*)d_ws;
    float* q    = ws;
    float* kbuf = ws + 3145728;
    float* vpre = ws + 6291456;
    float* vbuf = ws + 9437184;
    unsigned short* gsil = (unsigned short*)(ws + 12582912);
    unsigned short* WTh = (unsigned short*)(ws + 14155776);
    unsigned short* WTl = (unsigned short*)(ws + 17694720);
    float* w1f  = ws + 21233664;
    unsigned short* wcv = (unsigned short*)(ws + 14155776);
    float* X1g  = ws + 14155776;
    float* X2g  = ws + 17301504;
    float* Mg   = ws + 20447232;
    unsigned short* WG2Th = (unsigned short*)(ws + 22044672);
    unsigned short* WG2Tl = (unsigned short*)(ws + 22634496);
    unsigned short* w1h   = (unsigned short*)(ws + 23224320);
    unsigned short* w1l   = (unsigned short*)(ws + 23420928);
    float* bgraw = ws + 23617536;
    float* beta  = ws + 23666688;
    float* g     = ws + 23691264;
    float* csg   = ws + 23715840;
    unsigned short* hsbh = (unsigned short*)(ws + 9437184);
    unsigned short* hsbl = (unsigned short*)(ws + 11010048);
    unsigned short* WoTh = (unsigned short*)(ws);
    unsigned short* WoTl = (unsigned short*)(ws + 1179648);
    unsigned short* onh  = (unsigned short*)(ws + 6291456);
    unsigned short* onl  = (unsigned short*)(ws + 7864320);

    const dim3 blk(256);
    const dim3 blkT(32, 8);

    // P0: split hs; transsplit projection batch A = [Wq|Wk|Wv]
    splitcast_kernel<<<3072, blk, 0, stream>>>(hs, hsbh, hsbl, (T * HID) / 4);
    transsplit_kernel<<<dim3(48, 48), blkT, 0, stream>>>(Wq, WTh,               WTl,               1536, 1536);
    transsplit_kernel<<<dim3(48, 48), blkT, 0, stream>>>(Wk, WTh + 1536 * 1536, WTl + 1536 * 1536, 1536, 1536);
    transsplit_kernel<<<dim3(48, 48), blkT, 0, stream>>>(Wv, WTh + 3072 * 1536, WTl + 3072 * 1536, 1536, 1536);

    // P1a: q|k|v projection (N=4608)
    mgemm<1><<<dim3(36, 16), blk, 0, stream>>>(hsbh, hsbl, WTh, WTl, 1536, 4608,
        nullptr, nullptr, q, kbuf, vpre, nullptr, nullptr, nullptr);

    // P1b: gate|w1|bg projection (N=1792), reusing the WT buffer
    transsplit_kernel<<<dim3(48, 48), blkT, 0, stream>>>(Wgate, WTh,               WTl,               1536, 1536);
    transsplit_kernel<<<dim3(6, 48),  blkT, 0, stream>>>(Wg1,   WTh + 1536 * 1536, WTl + 1536 * 1536, 1536, 192);
    transsplit_kernel<<<dim3(1, 48),  blkT, 0, stream>>>(Wb,    WTh + 1728 * 1536, WTl + 1728 * 1536, 1536, 12);
    transsplit_kernel<<<dim3(1, 48),  blkT, 0, stream>>>(Wa,    WTh + 1740 * 1536, WTl + 1740 * 1536, 1536, 12);
    mgemm<2><<<dim3(14, 16), blk, 0, stream>>>(hsbh, hsbl, WTh, WTl, 1536, 1792,
        nullptr, nullptr, nullptr, nullptr, nullptr, gsil, w1f, bgraw);
    bg2_kernel<<<192, blk, 0, stream>>>(bgraw, A_log, dt_bias, beta, g);
    splitcast_kernel<<<384, blk, 0, stream>>>(w1f, w1h, w1l, (2048 * 192) / 4);

    // P2: conv weights GEMM (bf16 out) + conv
    transsplit_kernel<<<dim3(192, 6), blkT, 0, stream>>>(Wg2, WG2Th, WG2Tl, 192, 6144);
    mgemm<3><<<dim3(48, 16), blk, 0, stream>>>(w1h, w1l, WG2Th, WG2Tl, 192, 6144,
        nullptr, wcv, nullptr, nullptr, nullptr, nullptr, nullptr, nullptr);
    conv_kernel<<<(T * HID) / 256, blk, 0, stream>>>(vpre, wcv, vbuf);

    // P3: chunked delta rule
    chunkloc_kernel<<<dim3(NC, NH), blk, 0, stream>>>(q, kbuf, vbuf, g, beta,
                                                      X1g, X2g, Mg, csg);
    state_kernel<<<dim3(NH, 8), blk, 0, stream>>>(kbuf, q, X1g, X2g, csg, vbuf);
    transsplit_kernel<<<dim3(48, 48), blkT, 0, stream>>>(Wo, WoTh, WoTl, 1536, 1536);
    outk_kernel<<<dim3(NC, NH, 2), blk, 0, stream>>>(X1g, Mg, vbuf);

    // P4: norm + output GEMM
    normgate_kernel<<<6144, blk, 0, stream>>>(vbuf, gsil, norm_w, onh, onl);
    mgemm<0><<<dim3(12, 16), blk, 0, stream>>>(onh, onl, WoTh, WoTl, 1536, 1536,
        (float*)d_out, nullptr, nullptr, nullptr, nullptr, nullptr, nullptr, nullptr);
}

// Round 8
// 807.296 us; speedup vs baseline: 1.3142x; 1.0150x over previous
//
#include <hip/hip_runtime.h>
#include <hip/hip_bf16.h>
#include <math.h>

#define T     2048
#define HID   1536
#define NH    12
#define DK    128
#define DV    128
#define CONVK 4
#define CH    64
#define NC    32

typedef __attribute__((ext_vector_type(8))) short bf16x8;
typedef __attribute__((ext_vector_type(4))) float floatx4;

__device__ __forceinline__ float siluf(float x) {
    return x / (1.0f + __expf(-x));
}
__device__ __forceinline__ unsigned short f2bf(float f) {
    union { __hip_bfloat16 b; unsigned short u; } cv;
    cv.b = __float2bfloat16(f);
    return cv.u;
}
__device__ __forceinline__ float bf2f(unsigned short u) {
    union { unsigned int u; float f; } cv;
    cv.u = ((unsigned int)u) << 16;
    return cv.f;
}
__device__ __forceinline__ void gl_lds16(const void* g, void* l) {
    __builtin_amdgcn_global_load_lds(
        (const __attribute__((address_space(1))) void*)g,
        (__attribute__((address_space(3))) void*)l, 16, 0, 0);
}

// ---------------------------------------------------------------------------
// split fp32 -> (hi, lo) bf16 pair, vectorized x4
// ---------------------------------------------------------------------------
__global__ __launch_bounds__(256) void splitcast_kernel(const float* __restrict__ s,
                                                        unsigned short* __restrict__ hi,
                                                        unsigned short* __restrict__ lo,
                                                        int n4) {
    int i = blockIdx.x * 256 + threadIdx.x;
    if (i >= n4) return;
    float4 x = ((const float4*)s)[i];
    ushort4 h, l;
    h.x = f2bf(x.x); l.x = f2bf(x.x - bf2f(h.x));
    h.y = f2bf(x.y); l.y = f2bf(x.y - bf2f(h.y));
    h.z = f2bf(x.z); l.z = f2bf(x.z - bf2f(h.z));
    h.w = f2bf(x.w); l.w = f2bf(x.w - bf2f(h.w));
    ((ushort4*)hi)[i] = h;
    ((ushort4*)lo)[i] = l;
}

// ---------------------------------------------------------------------------
// transpose + split: src (K x N fp32) -> hi/lo (N x K bf16). K%32==0.
// ---------------------------------------------------------------------------
__global__ __launch_bounds__(256) void transsplit_kernel(const float* __restrict__ src,
                                                         unsigned short* __restrict__ hi,
                                                         unsigned short* __restrict__ lo,
                                                         int K, int N) {
    __shared__ float tile[32][33];
    const int k0 = blockIdx.y * 32, n0 = blockIdx.x * 32;
    const int tx = threadIdx.x, ty = threadIdx.y;
#pragma unroll
    for (int r = 0; r < 4; ++r) {
        int kk = k0 + ty + 8 * r, nn = n0 + tx;
        tile[ty + 8 * r][tx] = (nn < N) ? src[(size_t)kk * N + nn] : 0.0f;
    }
    __syncthreads();
#pragma unroll
    for (int r = 0; r < 4; ++r) {
        int nn = n0 + ty + 8 * r, kk = k0 + tx;
        if (nn < N) {
            float x = tile[tx][ty + 8 * r];
            unsigned short h = f2bf(x);
            hi[(size_t)nn * K + kk] = h;
            lo[(size_t)nn * K + kk] = f2bf(x - bf2f(h));
        }
    }
}

// ---------------------------------------------------------------------------
// Split-bf16 MFMA GEMM (effectively fp32): C = (Ah+Al)(Bh+Bl)^T, lo*lo dropped.
// ---------------------------------------------------------------------------
template<int EPI>
__global__ __launch_bounds__(256)
void mgemm(const unsigned short* __restrict__ Ah, const unsigned short* __restrict__ Al,
           const unsigned short* __restrict__ Bh, const unsigned short* __restrict__ Bl,
           int K, int N, float* __restrict__ C, unsigned short* __restrict__ Cb,
           float* __restrict__ qf, float* __restrict__ kf, float* __restrict__ vf,
           unsigned short* __restrict__ gsilb, float* __restrict__ w1f,
           float* __restrict__ bgraw)
{
    __shared__ unsigned short AsH[4096], AsL[4096], BsH[4096], BsL[4096];
    const int tid = threadIdx.x;
    const int wave = tid >> 6, lane = tid & 63;
    const int wr = wave >> 1, wc = wave & 1;
    const int lm = lane & 15, lq = lane >> 4;
    const int rowBase = blockIdx.y * 128, colBase = blockIdx.x * 128;

    floatx4 acc[4][4];
#pragma unroll
    for (int i = 0; i < 4; ++i)
#pragma unroll
        for (int j = 0; j < 4; ++j) acc[i][j] = (floatx4){0.f, 0.f, 0.f, 0.f};

    const int mt0 = wave * 2, mt1 = wave * 2 + 1;
    const size_t aOff0 = (size_t)(rowBase + mt0 * 16 + lm) * K + lq * 8;
    const size_t aOff1 = (size_t)(rowBase + mt1 * 16 + lm) * K + lq * 8;
    const size_t bOff0 = (size_t)(colBase + mt0 * 16 + lm) * K + lq * 8;
    const size_t bOff1 = (size_t)(colBase + mt1 * 16 + lm) * K + lq * 8;

    for (int k0 = 0; k0 < K; k0 += 32) {
        gl_lds16(Ah + aOff0 + k0, &AsH[mt0 * 512]);
        gl_lds16(Ah + aOff1 + k0, &AsH[mt1 * 512]);
        gl_lds16(Al + aOff0 + k0, &AsL[mt0 * 512]);
        gl_lds16(Al + aOff1 + k0, &AsL[mt1 * 512]);
        gl_lds16(Bh + bOff0 + k0, &BsH[mt0 * 512]);
        gl_lds16(Bh + bOff1 + k0, &BsH[mt1 * 512]);
        gl_lds16(Bl + bOff0 + k0, &BsL[mt0 * 512]);
        gl_lds16(Bl + bOff1 + k0, &BsL[mt1 * 512]);
        __syncthreads();
        bf16x8 ah[4], al[4], bh[4], bl[4];
#pragma unroll
        for (int i = 0; i < 4; ++i) {
            ah[i] = *(const bf16x8*)&AsH[(wr * 4 + i) * 512 + lane * 8];
            al[i] = *(const bf16x8*)&AsL[(wr * 4 + i) * 512 + lane * 8];
            bh[i] = *(const bf16x8*)&BsH[(wc * 4 + i) * 512 + lane * 8];
            bl[i] = *(const bf16x8*)&BsL[(wc * 4 + i) * 512 + lane * 8];
        }
#pragma unroll
        for (int mi = 0; mi < 4; ++mi)
#pragma unroll
            for (int ni = 0; ni < 4; ++ni) {
                acc[mi][ni] = __builtin_amdgcn_mfma_f32_16x16x32_bf16(
                    ah[mi], bh[ni], acc[mi][ni], 0, 0, 0);
                acc[mi][ni] = __builtin_amdgcn_mfma_f32_16x16x32_bf16(
                    ah[mi], bl[ni], acc[mi][ni], 0, 0, 0);
                acc[mi][ni] = __builtin_amdgcn_mfma_f32_16x16x32_bf16(
                    al[mi], bh[ni], acc[mi][ni], 0, 0, 0);
            }
        __syncthreads();
    }

#pragma unroll
    for (int mi = 0; mi < 4; ++mi)
#pragma unroll
        for (int ni = 0; ni < 4; ++ni) {
            const int col = colBase + wc * 64 + ni * 16 + lm;
#pragma unroll
            for (int r = 0; r < 4; ++r) {
                const int row = rowBase + wr * 64 + mi * 16 + lq * 4 + r;
                const float x = acc[mi][ni][r];
                if (EPI == 0) {
                    C[(size_t)row * N + col] = x;
                } else if (EPI == 3) {
                    Cb[(size_t)row * N + col] = f2bf(x);
                } else if (EPI == 1) {
                    if (col < 1536)       qf[(size_t)row * 1536 + col] = siluf(x);
                    else if (col < 3072)  kf[(size_t)row * 1536 + col - 1536] = siluf(x);
                    else                  vf[(size_t)row * 1536 + col - 3072] = x;
                } else {  // EPI == 2
                    if (col < 1536)       gsilb[(size_t)row * 1536 + col] = f2bf(siluf(x));
                    else if (col < 1728)  w1f[(size_t)row * 192 + col - 1536] = siluf(x);
                    else if (col < 1752)  bgraw[(size_t)row * 24 + col - 1728] = x;
                }
            }
        }
}

// ---------------------------------------------------------------------------
__global__ __launch_bounds__(256) void bg2_kernel(const float* __restrict__ bgraw,
                                                  const float* __restrict__ A_log,
                                                  const float* __restrict__ dt_bias,
                                                  float* __restrict__ beta,
                                                  float* __restrict__ g) {
    int idx = blockIdx.x * 256 + threadIdx.x;
    if (idx >= T * 24) return;
    int t = idx / 24, c = idx % 24;
    float x = bgraw[idx];
    if (c < 12) {
        beta[t * NH + c] = 1.0f / (1.0f + __expf(-x));
    } else {
        int h = c - 12;
        float y = x + dt_bias[h];
        float sp = (y > 20.0f) ? y : log1pf(__expf(y));
        g[t * NH + h] = -__expf(A_log[h]) * sp;
    }
}

// ---------------------------------------------------------------------------
__global__ __launch_bounds__(256) void conv_kernel(const float* __restrict__ vpre,
                                                   const unsigned short* __restrict__ w,
                                                   float* __restrict__ v) {
    const int idx = blockIdx.x * 256 + threadIdx.x;
    if (idx >= T * HID) return;
    const int t = idx / HID, d = idx % HID;
    const ushort4 wv = *(const ushort4*)(w + (size_t)t * (HID * CONVK) + d * 4);
    const float w4[4] = { bf2f(wv.x), bf2f(wv.y), bf2f(wv.z), bf2f(wv.w) };
    float acc = 0.0f;
#pragma unroll
    for (int i = 0; i < CONVK; i++) {
        const int ts = t - (CONVK - 1) + i;
        if (ts >= 0) acc += vpre[(size_t)ts * HID + d] * w4[i];
    }
    v[idx] = siluf(acc);
}

// ---------------------------------------------------------------------------
// D1: chunk-local WY precompute — MFMA version.
// grid (NC, NH), 256 thr. LDS 156.4 KB, 1 block/CU. 2 barriers.
// P0: stage K/Q as split hi/lo [i][dk] (A/B-op layout), K^T fp32, V fp32,
//     cs/sb/sbb prefix (wave 0).
// P1: A = tril_strict(beta_i e^{cs_i-cs_j} K K^T) via 3-term MFMA -> As fp32;
//     M = tril(e^{cs_i-cs_j} Q K^T) via MFMA -> global Mg;
//     xc RHS: col<128 -> sb*V col, col>=128 -> sbb*K^T col (fp32).
// P2: forward substitution (serial-in-i, per-thread column in registers),
//     store X1/X2, csg.
// ---------------------------------------------------------------------------
__global__ __launch_bounds__(256, 1) void chunkloc_kernel(
    const float* __restrict__ q, const float* __restrict__ k, const float* __restrict__ v,
    const float* __restrict__ g, const float* __restrict__ beta,
    float* __restrict__ X1g, float* __restrict__ X2g,
    float* __restrict__ Mg, float* __restrict__ csg)
{
    __shared__ unsigned short KhS[64 * 136], KlS[64 * 136];
    __shared__ unsigned short QhS[64 * 136], QlS[64 * 136];
    __shared__ float KT[128 * 68];
    __shared__ float Vs[64 * 132];
    __shared__ float As[64 * 68];
    __shared__ float cs[64], sb[64], sbb[64];

    const int c = blockIdx.x, h = blockIdx.y;
    const int tid = threadIdx.x;
    const int wave = tid >> 6, lane = tid & 63;
    const int lm = lane & 15, lq = lane >> 4;
    const int li = tid >> 2, lq4 = tid & 3;
    const size_t rowbase = (size_t)(c * CH) * HID + h * DK;

    // ---- P0: stage ----
    {
        const float* ksrc = k + rowbase + (size_t)li * HID + lq4 * 32;
        const float* qsrc = q + rowbase + (size_t)li * HID + lq4 * 32;
        const float* vsrc = v + (size_t)(c * CH + li) * HID + h * DV + lq4 * 32;
#pragma unroll
        for (int f = 0; f < 8; ++f) {
            float4 kx = *(const float4*)(ksrc + f * 4);
            float4 qx = *(const float4*)(qsrc + f * 4);
            float4 vx = *(const float4*)(vsrc + f * 4);
            const int d0 = lq4 * 32 + f * 4;
            {
                ushort4 hh, ll;
                hh.x = f2bf(kx.x); ll.x = f2bf(kx.x - bf2f(hh.x));
                hh.y = f2bf(kx.y); ll.y = f2bf(kx.y - bf2f(hh.y));
                hh.z = f2bf(kx.z); ll.z = f2bf(kx.z - bf2f(hh.z));
                hh.w = f2bf(kx.w); ll.w = f2bf(kx.w - bf2f(hh.w));
                *(ushort4*)&KhS[li * 136 + d0] = hh;
                *(ushort4*)&KlS[li * 136 + d0] = ll;
            }
            {
                ushort4 hh, ll;
                hh.x = f2bf(qx.x); ll.x = f2bf(qx.x - bf2f(hh.x));
                hh.y = f2bf(qx.y); ll.y = f2bf(qx.y - bf2f(hh.y));
                hh.z = f2bf(qx.z); ll.z = f2bf(qx.z - bf2f(hh.z));
                hh.w = f2bf(qx.w); ll.w = f2bf(qx.w - bf2f(hh.w));
                *(ushort4*)&QhS[li * 136 + d0] = hh;
                *(ushort4*)&QlS[li * 136 + d0] = ll;
            }
            KT[(d0 + 0) * 68 + li] = kx.x;
            KT[(d0 + 1) * 68 + li] = kx.y;
            KT[(d0 + 2) * 68 + li] = kx.z;
            KT[(d0 + 3) * 68 + li] = kx.w;
            *(float4*)&Vs[li * 132 + d0] = vx;
        }
    }
    if (tid < 64) {
        float gv = g[(c * CH + tid) * NH + h];
        float bv = beta[(c * CH + tid) * NH + h];
        float csv = gv;
#pragma unroll
        for (int off = 1; off < 64; off <<= 1) {
            float n = __shfl_up(csv, off);
            if (tid >= off) csv += n;
        }
        cs[tid] = csv; sb[tid] = bv; sbb[tid] = bv * __expf(csv);
    }
    __syncthreads();

    // ---- P1: MFMA A-phase and M-phase; xc RHS ----
    {
        const int ti = wave;
#pragma unroll
        for (int tj = 0; tj < 4; ++tj) {
            floatx4 acc = (floatx4){0.f, 0.f, 0.f, 0.f};
#pragma unroll
            for (int ks = 0; ks < 4; ++ks) {
                bf16x8 a_h = *(const bf16x8*)&KhS[(ti * 16 + lm) * 136 + ks * 32 + lq * 8];
                bf16x8 a_l = *(const bf16x8*)&KlS[(ti * 16 + lm) * 136 + ks * 32 + lq * 8];
                bf16x8 b_h = *(const bf16x8*)&KhS[(tj * 16 + lm) * 136 + ks * 32 + lq * 8];
                bf16x8 b_l = *(const bf16x8*)&KlS[(tj * 16 + lm) * 136 + ks * 32 + lq * 8];
                acc = __builtin_amdgcn_mfma_f32_16x16x32_bf16(a_h, b_h, acc, 0, 0, 0);
                acc = __builtin_amdgcn_mfma_f32_16x16x32_bf16(a_h, b_l, acc, 0, 0, 0);
                acc = __builtin_amdgcn_mfma_f32_16x16x32_bf16(a_l, b_h, acc, 0, 0, 0);
            }
#pragma unroll
            for (int r = 0; r < 4; ++r) {
                const int i = ti * 16 + lq * 4 + r, j = tj * 16 + lm;
                As[i * 68 + j] = (j < i) ? sb[i] * __expf(cs[i] - cs[j]) * acc[r] : 0.0f;
            }
        }
        const size_t mbase = (size_t)(h * NC + c) * CH * CH;
#pragma unroll
        for (int tj = 0; tj < 4; ++tj) {
            floatx4 acc = (floatx4){0.f, 0.f, 0.f, 0.f};
#pragma unroll
            for (int ks = 0; ks < 4; ++ks) {
                bf16x8 a_h = *(const bf16x8*)&QhS[(ti * 16 + lm) * 136 + ks * 32 + lq * 8];
                bf16x8 a_l = *(const bf16x8*)&QlS[(ti * 16 + lm) * 136 + ks * 32 + lq * 8];
                bf16x8 b_h = *(const bf16x8*)&KhS[(tj * 16 + lm) * 136 + ks * 32 + lq * 8];
                bf16x8 b_l = *(const bf16x8*)&KlS[(tj * 16 + lm) * 136 + ks * 32 + lq * 8];
                acc = __builtin_amdgcn_mfma_f32_16x16x32_bf16(a_h, b_h, acc, 0, 0, 0);
                acc = __builtin_amdgcn_mfma_f32_16x16x32_bf16(a_h, b_l, acc, 0, 0, 0);
                acc = __builtin_amdgcn_mfma_f32_16x16x32_bf16(a_l, b_h, acc, 0, 0, 0);
            }
#pragma unroll
            for (int r = 0; r < 4; ++r) {
                const int i = ti * 16 + lq * 4 + r, j = tj * 16 + lm;
                Mg[mbase + (size_t)i * 64 + j] =
                    (j <= i) ? __expf(cs[i] - cs[j]) * acc[r] : 0.0f;
            }
        }
    }

    float xc[64];
    const int col = tid;
    if (col < 128) {
#pragma unroll
        for (int i = 0; i < 64; ++i) xc[i] = sb[i] * Vs[i * 132 + col];
    } else {
        const int dcol = col - 128;
#pragma unroll
        for (int i4 = 0; i4 < 16; ++i4) {
            float4 kq = *(const float4*)&KT[dcol * 68 + i4 * 4];
            xc[i4 * 4 + 0] = sbb[i4 * 4 + 0] * kq.x;
            xc[i4 * 4 + 1] = sbb[i4 * 4 + 1] * kq.y;
            xc[i4 * 4 + 2] = sbb[i4 * 4 + 2] * kq.z;
            xc[i4 * 4 + 3] = sbb[i4 * 4 + 3] * kq.w;
        }
    }
    __syncthreads();

    // ---- P2: forward substitution + stores ----
#pragma unroll
    for (int i = 1; i < 64; ++i) {
        float a = xc[i];
#pragma unroll
        for (int j4 = 0; j4 < (i + 3) / 4; ++j4) {
            float4 a4 = *(const float4*)&As[i * 68 + j4 * 4];
            a -= a4.x * xc[j4 * 4 + 0] + a4.y * xc[j4 * 4 + 1]
               + a4.z * xc[j4 * 4 + 2] + a4.w * xc[j4 * 4 + 3];
        }
        xc[i] = a;
    }

    {
        const size_t xbase = (size_t)(h * NC + c) * CH * 128;
        if (col < 128) {
            for (int i = 0; i < 64; ++i) X1g[xbase + (size_t)i * 128 + col] = xc[i];
        } else {
            for (int i = 0; i < 64; ++i) X2g[xbase + (size_t)i * 128 + (col - 128)] = xc[i];
        }
    }
    if (tid < 64) csg[(size_t)(h * NC + c) * CH + tid] = cs[tid];
}

// ---------------------------------------------------------------------------
// D2: serial inter-chunk recurrence — split-bf16 MFMA version (verified R7)
// ---------------------------------------------------------------------------
__global__ __launch_bounds__(256, 1) void state_kernel(
    const float* __restrict__ k, const float* __restrict__ q,
    float* __restrict__ X1g /* in: X1, out: U */,
    const float* __restrict__ X2g, const float* __restrict__ csg,
    float* __restrict__ o)
{
    __shared__ unsigned short X2Ah[64 * 136], X2Al[64 * 136];  // -X2, A-op [i][dk]
    __shared__ unsigned short QAh [64 * 136], QAl [64 * 136];  //  Q,  A-op [i][dk]
    __shared__ unsigned short KTh [128 * 72], KTl [128 * 72];  //  K^T, A-op [dk][i]
    __shared__ unsigned short SBh [16 * 136], SBl [16 * 136];  //  S^T, B-op [dv][dk]
    __shared__ unsigned short UBh [16 * 72],  UBl [16 * 72];   //  U'^T, B-op [dv][i]
    __shared__ float St[16 * 132];                             //  S^T fp32 master
    __shared__ float scs[64];

    const int h = blockIdx.x, db = blockIdx.y;
    const int tid = threadIdx.x;
    const int wave = tid >> 6, lane = tid & 63;
    const int lm = lane & 15, lq = lane >> 4;    // MFMA fragment indices
    const int li = tid >> 2, lq4 = tid & 3;      // staging indices

    for (int idx = tid; idx < 16 * 132; idx += 256) St[idx] = 0.0f;
    for (int idx = tid; idx < 16 * 136; idx += 256) { SBh[idx] = 0; SBl[idx] = 0; }
    __syncthreads();

    for (int c = 0; c < NC; ++c) {
        const size_t hc = (size_t)(h * NC + c);
        const size_t xb = hc * CH * 128;

        // ---- phase 1: stage -X2, Q (A-layout), K^T, cs ----
        {
            if (tid < 64) scs[tid] = csg[hc * CH + tid];
            const float* x2p = X2g + xb + (size_t)li * 128 + lq4 * 32;
            const float* qp  = q + (size_t)(c * CH + li) * HID + h * DK + lq4 * 32;
            const float* kp  = k + (size_t)(c * CH + li) * HID + h * DK + lq4 * 32;
#pragma unroll
            for (int f = 0; f < 8; ++f) {
                float4 x2 = *(const float4*)(x2p + f * 4);
                float4 qq = *(const float4*)(qp + f * 4);
                float4 kk = *(const float4*)(kp + f * 4);
                const int dbase = lq4 * 32 + f * 4;
                {
                    const float v0 = -x2.x, v1 = -x2.y, v2 = -x2.z, v3 = -x2.w;
                    ushort4 hh, ll;
                    hh.x = f2bf(v0); ll.x = f2bf(v0 - bf2f(hh.x));
                    hh.y = f2bf(v1); ll.y = f2bf(v1 - bf2f(hh.y));
                    hh.z = f2bf(v2); ll.z = f2bf(v2 - bf2f(hh.z));
                    hh.w = f2bf(v3); ll.w = f2bf(v3 - bf2f(hh.w));
                    *(ushort4*)&X2Ah[li * 136 + dbase] = hh;
                    *(ushort4*)&X2Al[li * 136 + dbase] = ll;
                }
                {
                    ushort4 hh, ll;
                    hh.x = f2bf(qq.x); ll.x = f2bf(qq.x - bf2f(hh.x));
                    hh.y = f2bf(qq.y); ll.y = f2bf(qq.y - bf2f(hh.y));
                    hh.z = f2bf(qq.z); ll.z = f2bf(qq.z - bf2f(hh.z));
                    hh.w = f2bf(qq.w); ll.w = f2bf(qq.w - bf2f(hh.w));
                    *(ushort4*)&QAh[li * 136 + dbase] = hh;
                    *(ushort4*)&QAl[li * 136 + dbase] = ll;
                }
                {
                    const float kv[4] = {kk.x, kk.y, kk.z, kk.w};
#pragma unroll
                    for (int e = 0; e < 4; ++e) {
                        unsigned short hh = f2bf(kv[e]);
                        KTh[(dbase + e) * 72 + li] = hh;
                        KTl[(dbase + e) * 72 + li] = f2bf(kv[e] - bf2f(hh));
                    }
                }
            }
        }
        __syncthreads();

        // ---- phase 2: U + o1 via MFMA ----
        {
            const int mw = wave;
            floatx4 accU, accO = (floatx4){0.f, 0.f, 0.f, 0.f};
            {
                float x1r[4];
#pragma unroll
                for (int r = 0; r < 4; ++r)
                    x1r[r] = X1g[xb + (size_t)(mw * 16 + lq * 4 + r) * 128 + db * 16 + lm];
                accU = (floatx4){x1r[0], x1r[1], x1r[2], x1r[3]};
            }
#pragma unroll
            for (int ks = 0; ks < 4; ++ks) {
                bf16x8 xh = *(const bf16x8*)&X2Ah[(mw * 16 + lm) * 136 + ks * 32 + lq * 8];
                bf16x8 xl = *(const bf16x8*)&X2Al[(mw * 16 + lm) * 136 + ks * 32 + lq * 8];
                bf16x8 qh = *(const bf16x8*)&QAh [(mw * 16 + lm) * 136 + ks * 32 + lq * 8];
                bf16x8 ql = *(const bf16x8*)&QAl [(mw * 16 + lm) * 136 + ks * 32 + lq * 8];
                bf16x8 sh = *(const bf16x8*)&SBh[lm * 136 + ks * 32 + lq * 8];
                bf16x8 sl = *(const bf16x8*)&SBl[lm * 136 + ks * 32 + lq * 8];
                accU = __builtin_amdgcn_mfma_f32_16x16x32_bf16(xh, sh, accU, 0, 0, 0);
                accU = __builtin_amdgcn_mfma_f32_16x16x32_bf16(xh, sl, accU, 0, 0, 0);
                accU = __builtin_amdgcn_mfma_f32_16x16x32_bf16(xl, sh, accU, 0, 0, 0);
                accO = __builtin_amdgcn_mfma_f32_16x16x32_bf16(qh, sh, accO, 0, 0, 0);
                accO = __builtin_amdgcn_mfma_f32_16x16x32_bf16(qh, sl, accO, 0, 0, 0);
                accO = __builtin_amdgcn_mfma_f32_16x16x32_bf16(ql, sh, accO, 0, 0, 0);
            }
            const float cs63 = scs[63];
#pragma unroll
            for (int r = 0; r < 4; ++r) {
                const int row = mw * 16 + lq * 4 + r;
                const float u = accU[r];
                X1g[xb + (size_t)row * 128 + db * 16 + lm] = u;
                const float up = u * __expf(cs63 - scs[row]);
                unsigned short uh = f2bf(up);
                UBh[lm * 72 + row] = uh;
                UBl[lm * 72 + row] = f2bf(up - bf2f(uh));
                o[(size_t)(c * CH + row) * HID + h * DV + db * 16 + lm] =
                    __expf(scs[row]) * accO[r];
            }
        }
        __syncthreads();

        // ---- phase 3: S = exp(cs63)*S + K^T U' via MFMA ----
        {
            const float bC = __expf(scs[63]);
#pragma unroll
            for (int mt2 = 0; mt2 < 2; ++mt2) {
                const int mt = wave * 2 + mt2;
                floatx4 acc;
#pragma unroll
                for (int r = 0; r < 4; ++r)
                    acc[r] = bC * St[lm * 132 + mt * 16 + lq * 4 + r];
#pragma unroll
                for (int ks = 0; ks < 2; ++ks) {
                    bf16x8 ah = *(const bf16x8*)&KTh[(mt * 16 + lm) * 72 + ks * 32 + lq * 8];
                    bf16x8 al = *(const bf16x8*)&KTl[(mt * 16 + lm) * 72 + ks * 32 + lq * 8];
                    bf16x8 bh = *(const bf16x8*)&UBh[lm * 72 + ks * 32 + lq * 8];
                    bf16x8 bl = *(const bf16x8*)&UBl[lm * 72 + ks * 32 + lq * 8];
                    acc = __builtin_amdgcn_mfma_f32_16x16x32_bf16(ah, bh, acc, 0, 0, 0);
                    acc = __builtin_amdgcn_mfma_f32_16x16x32_bf16(ah, bl, acc, 0, 0, 0);
                    acc = __builtin_amdgcn_mfma_f32_16x16x32_bf16(al, bh, acc, 0, 0, 0);
                }
#pragma unroll
                for (int r = 0; r < 4; ++r) {
                    const int dk = mt * 16 + lq * 4 + r;
                    const float sv = acc[r];
                    St[lm * 132 + dk] = sv;
                    unsigned short sh = f2bf(sv);
                    SBh[lm * 136 + dk] = sh;
                    SBl[lm * 136 + dk] = f2bf(sv - bf2f(sh));
                }
            }
        }
        __syncthreads();
    }
}

// ---------------------------------------------------------------------------
// D3: o = scale * (o + M U), all fp32 (verified)
// ---------------------------------------------------------------------------
__global__ __launch_bounds__(256) void outk_kernel(
    const float* __restrict__ Ug, const float* __restrict__ Mg,
    float* __restrict__ o)
{
    __shared__ float Msh[64 * 68];
    __shared__ float Ush[64 * 68];

    const int c = blockIdx.x, h = blockIdx.y;
    const int dvb = blockIdx.z * 64;
    const int tid = threadIdx.x;
    const size_t hc = (size_t)(h * NC + c);

    for (int e = 0; e < 16; ++e) {
        int idx = e * 256 + tid;
        Msh[(idx >> 6) * 68 + (idx & 63)] = Mg[hc * CH * CH + idx];
    }
    for (int e = 0; e < 16; ++e) {
        int idx = e * 256 + tid;
        int j = idx >> 6, cc = idx & 63;
        Ush[j * 68 + cc] = Ug[hc * CH * 128 + (size_t)j * 128 + dvb + cc];
    }
    __syncthreads();

    const int tx = tid & 15, ty = tid >> 4;
    const int c0 = tx * 4, i0 = ty * 4;
    float acc[4][4] = {{0}};
    for (int j4 = 0; j4 < 16; ++j4) {
        float uv[4][4];
#pragma unroll
        for (int s = 0; s < 4; ++s) {
            float4 u4 = *(const float4*)&Ush[(j4 * 4 + s) * 68 + c0];
            uv[s][0] = u4.x; uv[s][1] = u4.y; uv[s][2] = u4.z; uv[s][3] = u4.w;
        }
#pragma unroll
        for (int r = 0; r < 4; ++r) {
            float4 m4 = *(const float4*)&Msh[(i0 + r) * 68 + j4 * 4];
            const float mv[4] = {m4.x, m4.y, m4.z, m4.w};
#pragma unroll
            for (int s = 0; s < 4; ++s)
#pragma unroll
                for (int e = 0; e < 4; ++e) acc[r][e] += mv[s] * uv[s][e];
        }
    }
    const float scale = 0.08838834764831845f;
#pragma unroll
    for (int r = 0; r < 4; ++r) {
        float* op = &o[(size_t)(c * CH + i0 + r) * HID + h * DV + dvb + c0];
        float4 prev = *(const float4*)op;
        float4 ov = make_float4(scale * (prev.x + acc[r][0]),
                                scale * (prev.y + acc[r][1]),
                                scale * (prev.z + acc[r][2]),
                                scale * (prev.w + acc[r][3]));
        *(float4*)op = ov;
    }
}

// ---------------------------------------------------------------------------
// Gated RMSNorm: gsil bf16 in, onorm (hi,lo) bf16 out
// ---------------------------------------------------------------------------
__global__ __launch_bounds__(256) void normgate_kernel(const float* __restrict__ o,
                                                       const unsigned short* __restrict__ gsil,
                                                       const float* __restrict__ nw,
                                                       unsigned short* __restrict__ out_hi,
                                                       unsigned short* __restrict__ out_lo) {
    const int gw = (blockIdx.x * 256 + threadIdx.x) >> 6;
    const int lane = threadIdx.x & 63;
    if (gw >= T * NH) return;
    const int t = gw / NH, h = gw % NH;
    const size_t base = (size_t)t * HID + h * DV;
    const float a = o[base + lane];
    const float b = o[base + lane + 64];
    float ss = a * a + b * b;
    ss += __shfl_xor(ss, 1);  ss += __shfl_xor(ss, 2);  ss += __shfl_xor(ss, 4);
    ss += __shfl_xor(ss, 8);  ss += __shfl_xor(ss, 16); ss += __shfl_xor(ss, 32);
    const float r = rsqrtf(ss * (1.0f / 128.0f) + 1e-5f);
    float va = a * r * nw[lane]      * bf2f(gsil[base + lane]);
    float vb = b * r * nw[lane + 64] * bf2f(gsil[base + lane + 64]);
    unsigned short ha = f2bf(va), hb = f2bf(vb);
    out_hi[base + lane]      = ha;  out_lo[base + lane]      = f2bf(va - bf2f(ha));
    out_hi[base + lane + 64] = hb;  out_lo[base + lane + 64] = f2bf(vb - bf2f(hb));
}

// ---------------------------------------------------------------------------
extern "C" void kernel_launch(void* const* d_in, const int* in_sizes, int n_in,
                              void* d_out, int out_size, void* d_ws, size_t ws_size,
                              hipStream_t stream) {
    const float* hs      = (const float*)d_in[0];
    const float* Wq      = (const float*)d_in[1];
    const float* Wk      = (const float*)d_in[2];
    const float* Wv      = (const float*)d_in[3];
    const float* Wb      = (const float*)d_in[4];
    const float* Wa      = (const float*)d_in[5];
    const float* A_log   = (const float*)d_in[6];
    const float* dt_bias = (const float*)d_in[7];
    const float* Wg1     = (const float*)d_in[8];
    const float* Wg2     = (const float*)d_in[9];
    const float* Wgate   = (const float*)d_in[10];
    const float* norm_w  = (const float*)d_in[11];
    const float* Wo      = (const float*)d_in[12];

    float* ws = (float*)d_ws;
    float* q    = ws;
    float* kbuf = ws + 3145728;
    float* vpre = ws + 6291456;
    float* vbuf = ws + 9437184;
    unsigned short* gsil = (unsigned short*)(ws + 12582912);
    unsigned short* WTh = (unsigned short*)(ws + 14155776);
    unsigned short* WTl = (unsigned short*)(ws + 17694720);
    float* w1f  = ws + 21233664;
    unsigned short* wcv = (unsigned short*)(ws + 14155776);
    float* X1g  = ws + 14155776;
    float* X2g  = ws + 17301504;
    float* Mg   = ws + 20447232;
    unsigned short* WG2Th = (unsigned short*)(ws + 22044672);
    unsigned short* WG2Tl = (unsigned short*)(ws + 22634496);
    unsigned short* w1h   = (unsigned short*)(ws + 23224320);
    unsigned short* w1l   = (unsigned short*)(ws + 23420928);
    float* bgraw = ws + 23617536;
    float* beta  = ws + 23666688;
    float* g     = ws + 23691264;
    float* csg   = ws + 23715840;
    unsigned short* hsbh = (unsigned short*)(ws + 9437184);
    unsigned short* hsbl = (unsigned short*)(ws + 11010048);
    unsigned short* WoTh = (unsigned short*)(ws);
    unsigned short* WoTl = (unsigned short*)(ws + 1179648);
    unsigned short* onh  = (unsigned short*)(ws + 6291456);
    unsigned short* onl  = (unsigned short*)(ws + 7864320);

    const dim3 blk(256);
    const dim3 blkT(32, 8);

    // P0: split hs; transsplit projection batch A = [Wq|Wk|Wv]
    splitcast_kernel<<<3072, blk, 0, stream>>>(hs, hsbh, hsbl, (T * HID) / 4);
    transsplit_kernel<<<dim3(48, 48), blkT, 0, stream>>>(Wq, WTh,               WTl,               1536, 1536);
    transsplit_kernel<<<dim3(48, 48), blkT, 0, stream>>>(Wk, WTh + 1536 * 1536, WTl + 1536 * 1536, 1536, 1536);
    transsplit_kernel<<<dim3(48, 48), blkT, 0, stream>>>(Wv, WTh + 3072 * 1536, WTl + 3072 * 1536, 1536, 1536);

    // P1a: q|k|v projection (N=4608)
    mgemm<1><<<dim3(36, 16), blk, 0, stream>>>(hsbh, hsbl, WTh, WTl, 1536, 4608,
        nullptr, nullptr, q, kbuf, vpre, nullptr, nullptr, nullptr);

    // P1b: gate|w1|bg projection (N=1792), reusing the WT buffer
    transsplit_kernel<<<dim3(48, 48), blkT, 0, stream>>>(Wgate, WTh,               WTl,               1536, 1536);
    transsplit_kernel<<<dim3(6, 48),  blkT, 0, stream>>>(Wg1,   WTh + 1536 * 1536, WTl + 1536 * 1536, 1536, 192);
    transsplit_kernel<<<dim3(1, 48),  blkT, 0, stream>>>(Wb,    WTh + 1728 * 1536, WTl + 1728 * 1536, 1536, 12);
    transsplit_kernel<<<dim3(1, 48),  blkT, 0, stream>>>(Wa,    WTh + 1740 * 1536, WTl + 1740 * 1536, 1536, 12);
    mgemm<2><<<dim3(14, 16), blk, 0, stream>>>(hsbh, hsbl, WTh, WTl, 1536, 1792,
        nullptr, nullptr, nullptr, nullptr, nullptr, gsil, w1f, bgraw);
    bg2_kernel<<<192, blk, 0, stream>>>(bgraw, A_log, dt_bias, beta, g);
    splitcast_kernel<<<384, blk, 0, stream>>>(w1f, w1h, w1l, (2048 * 192) / 4);

    // P2: conv weights GEMM (bf16 out) + conv
    transsplit_kernel<<<dim3(192, 6), blkT, 0, stream>>>(Wg2, WG2Th, WG2Tl, 192, 6144);
    mgemm<3><<<dim3(48, 16), blk, 0, stream>>>(w1h, w1l, WG2Th, WG2Tl, 192, 6144,
        nullptr, wcv, nullptr, nullptr, nullptr, nullptr, nullptr, nullptr);
    conv_kernel<<<(T * HID) / 256, blk, 0, stream>>>(vpre, wcv, vbuf);

    // P3: chunked delta rule
    chunkloc_kernel<<<dim3(NC, NH), blk, 0, stream>>>(q, kbuf, vbuf, g, beta,
                                                      X1g, X2g, Mg, csg);
    state_kernel<<<dim3(NH, 8), blk, 0, stream>>>(kbuf, q, X1g, X2g, csg, vbuf);
    transsplit_kernel<<<dim3(48, 48), blkT, 0, stream>>>(Wo, WoTh, WoTl, 1536, 1536);
    outk_kernel<<<dim3(NC, NH, 2), blk, 0, stream>>>(X1g, Mg, vbuf);

    // P4: norm + output GEMM
    normgate_kernel<<<6144, blk, 0, stream>>>(vbuf, gsil, norm_w, onh, onl);
    mgemm<0><<<dim3(12, 16), blk, 0, stream>>>(onh, onl, WoTh, WoTl, 1536, 1536,
        (float*)d_out, nullptr, nullptr, nullptr, nullptr, nullptr, nullptr, nullptr);
}

// Round 12
// 680.688 us; speedup vs baseline: 1.5586x; 1.1860x over previous
//
#include <hip/hip_runtime.h>
#include <hip/hip_bf16.h>
#include <math.h>

#define T     2048
#define HID   1536
#define NH    12
#define DK    128
#define DV    128
#define CONVK 4
#define CH    64
#define NC    32

typedef __attribute__((ext_vector_type(8))) short bf16x8;
typedef __attribute__((ext_vector_type(8))) _Float16 fp16x8;
typedef __attribute__((ext_vector_type(4))) float floatx4;

__device__ __forceinline__ float siluf(float x) {
    return x / (1.0f + __expf(-x));
}
__device__ __forceinline__ unsigned short f2bf(float f) {
    union { __hip_bfloat16 b; unsigned short u; } cv;
    cv.b = __float2bfloat16(f);
    return cv.u;
}
__device__ __forceinline__ float bf2f(unsigned short u) {
    union { unsigned int u; float f; } cv;
    cv.u = ((unsigned int)u) << 16;
    return cv.f;
}
__device__ __forceinline__ unsigned short f2h(float f) {
    union { _Float16 h; unsigned short u; } cv;
    cv.h = (_Float16)f;
    return cv.u;
}
__device__ __forceinline__ void gl_lds16(const void* g, void* l) {
    __builtin_amdgcn_global_load_lds(
        (const __attribute__((address_space(1))) void*)g,
        (__attribute__((address_space(3))) void*)l, 16, 0, 0);
}

// ---------------------------------------------------------------------------
// hs: fp32 -> bf16 hi, bf16 lo, fp16  (one pass)
// ---------------------------------------------------------------------------
__global__ __launch_bounds__(256) void splitcast3_kernel(const float* __restrict__ s,
                                                         unsigned short* __restrict__ hi,
                                                         unsigned short* __restrict__ lo,
                                                         unsigned short* __restrict__ h16,
                                                         int n4) {
    int i = blockIdx.x * 256 + threadIdx.x;
    if (i >= n4) return;
    float4 x = ((const float4*)s)[i];
    ushort4 h, l, f;
    h.x = f2bf(x.x); l.x = f2bf(x.x - bf2f(h.x)); f.x = f2h(x.x);
    h.y = f2bf(x.y); l.y = f2bf(x.y - bf2f(h.y)); f.y = f2h(x.y);
    h.z = f2bf(x.z); l.z = f2bf(x.z - bf2f(h.z)); f.z = f2h(x.z);
    h.w = f2bf(x.w); l.w = f2bf(x.w - bf2f(h.w)); f.w = f2h(x.w);
    ((ushort4*)hi)[i] = h;
    ((ushort4*)lo)[i] = l;
    ((ushort4*)h16)[i] = f;
}

// ---------------------------------------------------------------------------
// transpose + split: src (K x N fp32) -> hi/lo (N x K bf16). K%32==0.
// ---------------------------------------------------------------------------
__global__ __launch_bounds__(256) void transsplit_kernel(const float* __restrict__ src,
                                                         unsigned short* __restrict__ hi,
                                                         unsigned short* __restrict__ lo,
                                                         int K, int N) {
    __shared__ float tile[32][33];
    const int k0 = blockIdx.y * 32, n0 = blockIdx.x * 32;
    const int tx = threadIdx.x, ty = threadIdx.y;
#pragma unroll
    for (int r = 0; r < 4; ++r) {
        int kk = k0 + ty + 8 * r, nn = n0 + tx;
        tile[ty + 8 * r][tx] = (nn < N) ? src[(size_t)kk * N + nn] : 0.0f;
    }
    __syncthreads();
#pragma unroll
    for (int r = 0; r < 4; ++r) {
        int nn = n0 + ty + 8 * r, kk = k0 + tx;
        if (nn < N) {
            float x = tile[tx][ty + 8 * r];
            unsigned short h = f2bf(x);
            hi[(size_t)nn * K + kk] = h;
            lo[(size_t)nn * K + kk] = f2bf(x - bf2f(h));
        }
    }
}

// ---------------------------------------------------------------------------
// transpose + cast fp16: src (K x N fp32) -> dst (N x K fp16).
// ---------------------------------------------------------------------------
__global__ __launch_bounds__(256) void transcasth_kernel(const float* __restrict__ src,
                                                         unsigned short* __restrict__ dst,
                                                         int K, int N) {
    __shared__ float tile[32][33];
    const int k0 = blockIdx.y * 32, n0 = blockIdx.x * 32;
    const int tx = threadIdx.x, ty = threadIdx.y;
#pragma unroll
    for (int r = 0; r < 4; ++r) {
        int kk = k0 + ty + 8 * r, nn = n0 + tx;
        tile[ty + 8 * r][tx] = (nn < N) ? src[(size_t)kk * N + nn] : 0.0f;
    }
    __syncthreads();
#pragma unroll
    for (int r = 0; r < 4; ++r) {
        int nn = n0 + ty + 8 * r, kk = k0 + tx;
        if (nn < N) dst[(size_t)nn * K + kk] = f2h(tile[tx][ty + 8 * r]);
    }
}

// ---------------------------------------------------------------------------
// MFMA GEMM, 128x128 tile, BK=32, 256 thr. A: M x K, B: N x K.
// MODE 0: single fp16 (1 MFMA)          — A/B are fp16 buffers.
// MODE 1: 3-term bf16 split (eff. fp32) — A/B are bf16 hi/lo buffers.
// EPI 0: C fp32.  EPI 1: q|v|gate|w1(fp16).  EPI 2: k|bg.  EPI 3: Cb bf16.
// ---------------------------------------------------------------------------
template<int EPI, int MODE>
__global__ __launch_bounds__(256)
void mgemm(const unsigned short* __restrict__ Ah, const unsigned short* __restrict__ Al,
           const unsigned short* __restrict__ Bh, const unsigned short* __restrict__ Bl,
           int K, int N, float* __restrict__ C, unsigned short* __restrict__ Cb,
           float* __restrict__ qf, float* __restrict__ vf, float* __restrict__ kf,
           unsigned short* __restrict__ gsilb, unsigned short* __restrict__ w1h16,
           float* __restrict__ bgraw)
{
    __shared__ unsigned short AsH[4096], BsH[4096];
    __shared__ unsigned short AsL[MODE ? 4096 : 4], BsL[MODE ? 4096 : 4];
    const int tid = threadIdx.x;
    const int wave = tid >> 6, lane = tid & 63;
    const int wr = wave >> 1, wc = wave & 1;
    const int lm = lane & 15, lq = lane >> 4;
    const int rowBase = blockIdx.y * 128, colBase = blockIdx.x * 128;

    floatx4 acc[4][4];
#pragma unroll
    for (int i = 0; i < 4; ++i)
#pragma unroll
        for (int j = 0; j < 4; ++j) acc[i][j] = (floatx4){0.f, 0.f, 0.f, 0.f};

    const int mt0 = wave * 2, mt1 = wave * 2 + 1;
    const size_t aOff0 = (size_t)(rowBase + mt0 * 16 + lm) * K + lq * 8;
    const size_t aOff1 = (size_t)(rowBase + mt1 * 16 + lm) * K + lq * 8;
    const size_t bOff0 = (size_t)(colBase + mt0 * 16 + lm) * K + lq * 8;
    const size_t bOff1 = (size_t)(colBase + mt1 * 16 + lm) * K + lq * 8;

    for (int k0 = 0; k0 < K; k0 += 32) {
        gl_lds16(Ah + aOff0 + k0, &AsH[mt0 * 512]);
        gl_lds16(Ah + aOff1 + k0, &AsH[mt1 * 512]);
        gl_lds16(Bh + bOff0 + k0, &BsH[mt0 * 512]);
        gl_lds16(Bh + bOff1 + k0, &BsH[mt1 * 512]);
        if (MODE) {
            gl_lds16(Al + aOff0 + k0, &AsL[mt0 * 512]);
            gl_lds16(Al + aOff1 + k0, &AsL[mt1 * 512]);
            gl_lds16(Bl + bOff0 + k0, &BsL[mt0 * 512]);
            gl_lds16(Bl + bOff1 + k0, &BsL[mt1 * 512]);
        }
        __syncthreads();
        if (MODE == 0) {
            fp16x8 a[4], b[4];
#pragma unroll
            for (int i = 0; i < 4; ++i) {
                a[i] = *(const fp16x8*)&AsH[(wr * 4 + i) * 512 + lane * 8];
                b[i] = *(const fp16x8*)&BsH[(wc * 4 + i) * 512 + lane * 8];
            }
#pragma unroll
            for (int mi = 0; mi < 4; ++mi)
#pragma unroll
                for (int ni = 0; ni < 4; ++ni)
                    acc[mi][ni] = __builtin_amdgcn_mfma_f32_16x16x32_f16(
                        a[mi], b[ni], acc[mi][ni], 0, 0, 0);
        } else {
            bf16x8 ah[4], al[4], bh[4], bl[4];
#pragma unroll
            for (int i = 0; i < 4; ++i) {
                ah[i] = *(const bf16x8*)&AsH[(wr * 4 + i) * 512 + lane * 8];
                bh[i] = *(const bf16x8*)&BsH[(wc * 4 + i) * 512 + lane * 8];
                al[i] = *(const bf16x8*)&AsL[(wr * 4 + i) * 512 + lane * 8];
                bl[i] = *(const bf16x8*)&BsL[(wc * 4 + i) * 512 + lane * 8];
            }
#pragma unroll
            for (int mi = 0; mi < 4; ++mi)
#pragma unroll
                for (int ni = 0; ni < 4; ++ni) {
                    acc[mi][ni] = __builtin_amdgcn_mfma_f32_16x16x32_bf16(
                        ah[mi], bh[ni], acc[mi][ni], 0, 0, 0);
                    acc[mi][ni] = __builtin_amdgcn_mfma_f32_16x16x32_bf16(
                        al[mi], bh[ni], acc[mi][ni], 0, 0, 0);
                    acc[mi][ni] = __builtin_amdgcn_mfma_f32_16x16x32_bf16(
                        ah[mi], bl[ni], acc[mi][ni], 0, 0, 0);
                }
        }
        __syncthreads();
    }

#pragma unroll
    for (int mi = 0; mi < 4; ++mi)
#pragma unroll
        for (int ni = 0; ni < 4; ++ni) {
            const int col = colBase + wc * 64 + ni * 16 + lm;
#pragma unroll
            for (int r = 0; r < 4; ++r) {
                const int row = rowBase + wr * 64 + mi * 16 + lq * 4 + r;
                const float x = acc[mi][ni][r];
                if (EPI == 0) {
                    C[(size_t)row * N + col] = x;
                } else if (EPI == 3) {
                    Cb[(size_t)row * N + col] = f2bf(x);
                } else if (EPI == 1) {
                    if (col < 1536)       qf[(size_t)row * 1536 + col] = siluf(x);
                    else if (col < 3072)  vf[(size_t)row * 1536 + col - 1536] = x;
                    else if (col < 4608)  gsilb[(size_t)row * 1536 + col - 3072] = f2bf(siluf(x));
                    else if (col < 4800)  w1h16[(size_t)row * 192 + col - 4608] = f2h(siluf(x));
                } else {  // EPI == 2: k | bg
                    if (col < 1536)       kf[(size_t)row * 1536 + col] = siluf(x);
                    else if (col < 1560)  bgraw[(size_t)row * 24 + col - 1536] = x;
                }
            }
        }
}

// ---------------------------------------------------------------------------
__global__ __launch_bounds__(256) void bg2_kernel(const float* __restrict__ bgraw,
                                                  const float* __restrict__ A_log,
                                                  const float* __restrict__ dt_bias,
                                                  float* __restrict__ beta,
                                                  float* __restrict__ g) {
    int idx = blockIdx.x * 256 + threadIdx.x;
    if (idx >= T * 24) return;
    int t = idx / 24, c = idx % 24;
    float x = bgraw[idx];
    if (c < 12) {
        beta[t * NH + c] = 1.0f / (1.0f + __expf(-x));
    } else {
        int h = c - 12;
        float y = x + dt_bias[h];
        float sp = (y > 20.0f) ? y : log1pf(__expf(y));
        g[t * NH + h] = -__expf(A_log[h]) * sp;
    }
}

// ---------------------------------------------------------------------------
__global__ __launch_bounds__(256) void conv_kernel(const float* __restrict__ vpre,
                                                   const unsigned short* __restrict__ w,
                                                   float* __restrict__ v) {
    const int idx = blockIdx.x * 256 + threadIdx.x;
    if (idx >= T * HID) return;
    const int t = idx / HID, d = idx % HID;
    const ushort4 wv = *(const ushort4*)(w + (size_t)t * (HID * CONVK) + d * 4);
    const float w4[4] = { bf2f(wv.x), bf2f(wv.y), bf2f(wv.z), bf2f(wv.w) };
    float acc = 0.0f;
#pragma unroll
    for (int i = 0; i < CONVK; i++) {
        const int ts = t - (CONVK - 1) + i;
        if (ts >= 0) acc += vpre[(size_t)ts * HID + d] * w4[i];
    }
    v[idx] = siluf(acc);
}

// ---------------------------------------------------------------------------
// D1: chunk-local WY precompute — MFMA version (verified R8)
// ---------------------------------------------------------------------------
__global__ __launch_bounds__(256, 1) void chunkloc_kernel(
    const float* __restrict__ q, const float* __restrict__ k, const float* __restrict__ v,
    const float* __restrict__ g, const float* __restrict__ beta,
    float* __restrict__ X1g, float* __restrict__ X2g,
    float* __restrict__ Mg, float* __restrict__ csg)
{
    __shared__ unsigned short KhS[64 * 136], KlS[64 * 136];
    __shared__ unsigned short QhS[64 * 136], QlS[64 * 136];
    __shared__ float KT[128 * 68];
    __shared__ float Vs[64 * 132];
    __shared__ float As[64 * 68];
    __shared__ float cs[64], sb[64], sbb[64];

    const int c = blockIdx.x, h = blockIdx.y;
    const int tid = threadIdx.x;
    const int wave = tid >> 6, lane = tid & 63;
    const int lm = lane & 15, lq = lane >> 4;
    const int li = tid >> 2, lq4 = tid & 3;
    const size_t rowbase = (size_t)(c * CH) * HID + h * DK;

    {
        const float* ksrc = k + rowbase + (size_t)li * HID + lq4 * 32;
        const float* qsrc = q + rowbase + (size_t)li * HID + lq4 * 32;
        const float* vsrc = v + (size_t)(c * CH + li) * HID + h * DV + lq4 * 32;
#pragma unroll
        for (int f = 0; f < 8; ++f) {
            float4 kx = *(const float4*)(ksrc + f * 4);
            float4 qx = *(const float4*)(qsrc + f * 4);
            float4 vx = *(const float4*)(vsrc + f * 4);
            const int d0 = lq4 * 32 + f * 4;
            {
                ushort4 hh, ll;
                hh.x = f2bf(kx.x); ll.x = f2bf(kx.x - bf2f(hh.x));
                hh.y = f2bf(kx.y); ll.y = f2bf(kx.y - bf2f(hh.y));
                hh.z = f2bf(kx.z); ll.z = f2bf(kx.z - bf2f(hh.z));
                hh.w = f2bf(kx.w); ll.w = f2bf(kx.w - bf2f(hh.w));
                *(ushort4*)&KhS[li * 136 + d0] = hh;
                *(ushort4*)&KlS[li * 136 + d0] = ll;
            }
            {
                ushort4 hh, ll;
                hh.x = f2bf(qx.x); ll.x = f2bf(qx.x - bf2f(hh.x));
                hh.y = f2bf(qx.y); ll.y = f2bf(qx.y - bf2f(hh.y));
                hh.z = f2bf(qx.z); ll.z = f2bf(qx.z - bf2f(hh.z));
                hh.w = f2bf(qx.w); ll.w = f2bf(qx.w - bf2f(hh.w));
                *(ushort4*)&QhS[li * 136 + d0] = hh;
                *(ushort4*)&QlS[li * 136 + d0] = ll;
            }
            KT[(d0 + 0) * 68 + li] = kx.x;
            KT[(d0 + 1) * 68 + li] = kx.y;
            KT[(d0 + 2) * 68 + li] = kx.z;
            KT[(d0 + 3) * 68 + li] = kx.w;
            *(float4*)&Vs[li * 132 + d0] = vx;
        }
    }
    if (tid < 64) {
        float gv = g[(c * CH + tid) * NH + h];
        float bv = beta[(c * CH + tid) * NH + h];
        float csv = gv;
#pragma unroll
        for (int off = 1; off < 64; off <<= 1) {
            float n = __shfl_up(csv, off);
            if (tid >= off) csv += n;
        }
        cs[tid] = csv; sb[tid] = bv; sbb[tid] = bv * __expf(csv);
    }
    __syncthreads();

    {
        const int ti = wave;
#pragma unroll
        for (int tj = 0; tj < 4; ++tj) {
            floatx4 acc = (floatx4){0.f, 0.f, 0.f, 0.f};
#pragma unroll
            for (int ks = 0; ks < 4; ++ks) {
                bf16x8 a_h = *(const bf16x8*)&KhS[(ti * 16 + lm) * 136 + ks * 32 + lq * 8];
                bf16x8 a_l = *(const bf16x8*)&KlS[(ti * 16 + lm) * 136 + ks * 32 + lq * 8];
                bf16x8 b_h = *(const bf16x8*)&KhS[(tj * 16 + lm) * 136 + ks * 32 + lq * 8];
                bf16x8 b_l = *(const bf16x8*)&KlS[(tj * 16 + lm) * 136 + ks * 32 + lq * 8];
                acc = __builtin_amdgcn_mfma_f32_16x16x32_bf16(a_h, b_h, acc, 0, 0, 0);
                acc = __builtin_amdgcn_mfma_f32_16x16x32_bf16(a_h, b_l, acc, 0, 0, 0);
                acc = __builtin_amdgcn_mfma_f32_16x16x32_bf16(a_l, b_h, acc, 0, 0, 0);
            }
#pragma unroll
            for (int r = 0; r < 4; ++r) {
                const int i = ti * 16 + lq * 4 + r, j = tj * 16 + lm;
                As[i * 68 + j] = (j < i) ? sb[i] * __expf(cs[i] - cs[j]) * acc[r] : 0.0f;
            }
        }
        const size_t mbase = (size_t)(h * NC + c) * CH * CH;
#pragma unroll
        for (int tj = 0; tj < 4; ++tj) {
            floatx4 acc = (floatx4){0.f, 0.f, 0.f, 0.f};
#pragma unroll
            for (int ks = 0; ks < 4; ++ks) {
                bf16x8 a_h = *(const bf16x8*)&QhS[(ti * 16 + lm) * 136 + ks * 32 + lq * 8];
                bf16x8 a_l = *(const bf16x8*)&QlS[(ti * 16 + lm) * 136 + ks * 32 + lq * 8];
                bf16x8 b_h = *(const bf16x8*)&KhS[(tj * 16 + lm) * 136 + ks * 32 + lq * 8];
                bf16x8 b_l = *(const bf16x8*)&KlS[(tj * 16 + lm) * 136 + ks * 32 + lq * 8];
                acc = __builtin_amdgcn_mfma_f32_16x16x32_bf16(a_h, b_h, acc, 0, 0, 0);
                acc = __builtin_amdgcn_mfma_f32_16x16x32_bf16(a_h, b_l, acc, 0, 0, 0);
                acc = __builtin_amdgcn_mfma_f32_16x16x32_bf16(a_l, b_h, acc, 0, 0, 0);
            }
#pragma unroll
            for (int r = 0; r < 4; ++r) {
                const int i = ti * 16 + lq * 4 + r, j = tj * 16 + lm;
                Mg[mbase + (size_t)i * 64 + j] =
                    (j <= i) ? __expf(cs[i] - cs[j]) * acc[r] : 0.0f;
            }
        }
    }

    float xc[64];
    const int col = tid;
    if (col < 128) {
#pragma unroll
        for (int i = 0; i < 64; ++i) xc[i] = sb[i] * Vs[i * 132 + col];
    } else {
        const int dcol = col - 128;
#pragma unroll
        for (int i4 = 0; i4 < 16; ++i4) {
            float4 kq = *(const float4*)&KT[dcol * 68 + i4 * 4];
            xc[i4 * 4 + 0] = sbb[i4 * 4 + 0] * kq.x;
            xc[i4 * 4 + 1] = sbb[i4 * 4 + 1] * kq.y;
            xc[i4 * 4 + 2] = sbb[i4 * 4 + 2] * kq.z;
            xc[i4 * 4 + 3] = sbb[i4 * 4 + 3] * kq.w;
        }
    }
    __syncthreads();

#pragma unroll
    for (int i = 1; i < 64; ++i) {
        float a = xc[i];
#pragma unroll
        for (int j4 = 0; j4 < (i + 3) / 4; ++j4) {
            float4 a4 = *(const float4*)&As[i * 68 + j4 * 4];
            a -= a4.x * xc[j4 * 4 + 0] + a4.y * xc[j4 * 4 + 1]
               + a4.z * xc[j4 * 4 + 2] + a4.w * xc[j4 * 4 + 3];
        }
        xc[i] = a;
    }

    {
        const size_t xbase = (size_t)(h * NC + c) * CH * 128;
        if (col < 128) {
            for (int i = 0; i < 64; ++i) X1g[xbase + (size_t)i * 128 + col] = xc[i];
        } else {
            for (int i = 0; i < 64; ++i) X2g[xbase + (size_t)i * 128 + (col - 128)] = xc[i];
        }
    }
    if (tid < 64) csg[(size_t)(h * NC + c) * CH + tid] = cs[tid];
}

// ---------------------------------------------------------------------------
// D2: serial inter-chunk recurrence — split-bf16 MFMA version (verified R7)
// ---------------------------------------------------------------------------
__global__ __launch_bounds__(256, 1) void state_kernel(
    const float* __restrict__ k, const float* __restrict__ q,
    float* __restrict__ X1g /* in: X1, out: U */,
    const float* __restrict__ X2g, const float* __restrict__ csg,
    float* __restrict__ o)
{
    __shared__ unsigned short X2Ah[64 * 136], X2Al[64 * 136];
    __shared__ unsigned short QAh [64 * 136], QAl [64 * 136];
    __shared__ unsigned short KTh [128 * 72], KTl [128 * 72];
    __shared__ unsigned short SBh [16 * 136], SBl [16 * 136];
    __shared__ unsigned short UBh [16 * 72],  UBl [16 * 72];
    __shared__ float St[16 * 132];
    __shared__ float scs[64];

    const int h = blockIdx.x, db = blockIdx.y;
    const int tid = threadIdx.x;
    const int wave = tid >> 6, lane = tid & 63;
    const int lm = lane & 15, lq = lane >> 4;
    const int li = tid >> 2, lq4 = tid & 3;

    for (int idx = tid; idx < 16 * 132; idx += 256) St[idx] = 0.0f;
    for (int idx = tid; idx < 16 * 136; idx += 256) { SBh[idx] = 0; SBl[idx] = 0; }
    __syncthreads();

    for (int c = 0; c < NC; ++c) {
        const size_t hc = (size_t)(h * NC + c);
        const size_t xb = hc * CH * 128;

        {
            if (tid < 64) scs[tid] = csg[hc * CH + tid];
            const float* x2p = X2g + xb + (size_t)li * 128 + lq4 * 32;
            const float* qp  = q + (size_t)(c * CH + li) * HID + h * DK + lq4 * 32;
            const float* kp  = k + (size_t)(c * CH + li) * HID + h * DK + lq4 * 32;
#pragma unroll
            for (int f = 0; f < 8; ++f) {
                float4 x2 = *(const float4*)(x2p + f * 4);
                float4 qq = *(const float4*)(qp + f * 4);
                float4 kk = *(const float4*)(kp + f * 4);
                const int dbase = lq4 * 32 + f * 4;
                {
                    const float v0 = -x2.x, v1 = -x2.y, v2 = -x2.z, v3 = -x2.w;
                    ushort4 hh, ll;
                    hh.x = f2bf(v0); ll.x = f2bf(v0 - bf2f(hh.x));
                    hh.y = f2bf(v1); ll.y = f2bf(v1 - bf2f(hh.y));
                    hh.z = f2bf(v2); ll.z = f2bf(v2 - bf2f(hh.z));
                    hh.w = f2bf(v3); ll.w = f2bf(v3 - bf2f(hh.w));
                    *(ushort4*)&X2Ah[li * 136 + dbase] = hh;
                    *(ushort4*)&X2Al[li * 136 + dbase] = ll;
                }
                {
                    ushort4 hh, ll;
                    hh.x = f2bf(qq.x); ll.x = f2bf(qq.x - bf2f(hh.x));
                    hh.y = f2bf(qq.y); ll.y = f2bf(qq.y - bf2f(hh.y));
                    hh.z = f2bf(qq.z); ll.z = f2bf(qq.z - bf2f(hh.z));
                    hh.w = f2bf(qq.w); ll.w = f2bf(qq.w - bf2f(hh.w));
                    *(ushort4*)&QAh[li * 136 + dbase] = hh;
                    *(ushort4*)&QAl[li * 136 + dbase] = ll;
                }
                {
                    const float kv[4] = {kk.x, kk.y, kk.z, kk.w};
#pragma unroll
                    for (int e = 0; e < 4; ++e) {
                        unsigned short hh = f2bf(kv[e]);
                        KTh[(dbase + e) * 72 + li] = hh;
                        KTl[(dbase + e) * 72 + li] = f2bf(kv[e] - bf2f(hh));
                    }
                }
            }
        }
        __syncthreads();

        {
            const int mw = wave;
            floatx4 accU, accO = (floatx4){0.f, 0.f, 0.f, 0.f};
            {
                float x1r[4];
#pragma unroll
                for (int r = 0; r < 4; ++r)
                    x1r[r] = X1g[xb + (size_t)(mw * 16 + lq * 4 + r) * 128 + db * 16 + lm];
                accU = (floatx4){x1r[0], x1r[1], x1r[2], x1r[3]};
            }
#pragma unroll
            for (int ks = 0; ks < 4; ++ks) {
                bf16x8 xh = *(const bf16x8*)&X2Ah[(mw * 16 + lm) * 136 + ks * 32 + lq * 8];
                bf16x8 xl = *(const bf16x8*)&X2Al[(mw * 16 + lm) * 136 + ks * 32 + lq * 8];
                bf16x8 qh = *(const bf16x8*)&QAh [(mw * 16 + lm) * 136 + ks * 32 + lq * 8];
                bf16x8 ql = *(const bf16x8*)&QAl [(mw * 16 + lm) * 136 + ks * 32 + lq * 8];
                bf16x8 sh = *(const bf16x8*)&SBh[lm * 136 + ks * 32 + lq * 8];
                bf16x8 sl = *(const bf16x8*)&SBl[lm * 136 + ks * 32 + lq * 8];
                accU = __builtin_amdgcn_mfma_f32_16x16x32_bf16(xh, sh, accU, 0, 0, 0);
                accU = __builtin_amdgcn_mfma_f32_16x16x32_bf16(xh, sl, accU, 0, 0, 0);
                accU = __builtin_amdgcn_mfma_f32_16x16x32_bf16(xl, sh, accU, 0, 0, 0);
                accO = __builtin_amdgcn_mfma_f32_16x16x32_bf16(qh, sh, accO, 0, 0, 0);
                accO = __builtin_amdgcn_mfma_f32_16x16x32_bf16(qh, sl, accO, 0, 0, 0);
                accO = __builtin_amdgcn_mfma_f32_16x16x32_bf16(ql, sh, accO, 0, 0, 0);
            }
            const float cs63 = scs[63];
#pragma unroll
            for (int r = 0; r < 4; ++r) {
                const int row = mw * 16 + lq * 4 + r;
                const float u = accU[r];
                X1g[xb + (size_t)row * 128 + db * 16 + lm] = u;
                const float up = u * __expf(cs63 - scs[row]);
                unsigned short uh = f2bf(up);
                UBh[lm * 72 + row] = uh;
                UBl[lm * 72 + row] = f2bf(up - bf2f(uh));
                o[(size_t)(c * CH + row) * HID + h * DV + db * 16 + lm] =
                    __expf(scs[row]) * accO[r];
            }
        }
        __syncthreads();

        {
            const float bC = __expf(scs[63]);
#pragma unroll
            for (int mt2 = 0; mt2 < 2; ++mt2) {
                const int mt = wave * 2 + mt2;
                floatx4 acc;
#pragma unroll
                for (int r = 0; r < 4; ++r)
                    acc[r] = bC * St[lm * 132 + mt * 16 + lq * 4 + r];
#pragma unroll
                for (int ks = 0; ks < 2; ++ks) {
                    bf16x8 ah = *(const bf16x8*)&KTh[(mt * 16 + lm) * 72 + ks * 32 + lq * 8];
                    bf16x8 al = *(const bf16x8*)&KTl[(mt * 16 + lm) * 72 + ks * 32 + lq * 8];
                    bf16x8 bh = *(const bf16x8*)&UBh[lm * 72 + ks * 32 + lq * 8];
                    bf16x8 bl = *(const bf16x8*)&UBl[lm * 72 + ks * 32 + lq * 8];
                    acc = __builtin_amdgcn_mfma_f32_16x16x32_bf16(ah, bh, acc, 0, 0, 0);
                    acc = __builtin_amdgcn_mfma_f32_16x16x32_bf16(ah, bl, acc, 0, 0, 0);
                    acc = __builtin_amdgcn_mfma_f32_16x16x32_bf16(al, bh, acc, 0, 0, 0);
                }
#pragma unroll
                for (int r = 0; r < 4; ++r) {
                    const int dk = mt * 16 + lq * 4 + r;
                    const float sv = acc[r];
                    St[lm * 132 + dk] = sv;
                    unsigned short sh = f2bf(sv);
                    SBh[lm * 136 + dk] = sh;
                    SBl[lm * 136 + dk] = f2bf(sv - bf2f(sh));
                }
            }
        }
        __syncthreads();
    }
}

// ---------------------------------------------------------------------------
// D3: o = scale * (o + M U), all fp32 (verified)
// ---------------------------------------------------------------------------
__global__ __launch_bounds__(256) void outk_kernel(
    const float* __restrict__ Ug, const float* __restrict__ Mg,
    float* __restrict__ o)
{
    __shared__ float Msh[64 * 68];
    __shared__ float Ush[64 * 68];

    const int c = blockIdx.x, h = blockIdx.y;
    const int dvb = blockIdx.z * 64;
    const int tid = threadIdx.x;
    const size_t hc = (size_t)(h * NC + c);

    for (int e = 0; e < 16; ++e) {
        int idx = e * 256 + tid;
        Msh[(idx >> 6) * 68 + (idx & 63)] = Mg[hc * CH * CH + idx];
    }
    for (int e = 0; e < 16; ++e) {
        int idx = e * 256 + tid;
        int j = idx >> 6, cc = idx & 63;
        Ush[j * 68 + cc] = Ug[hc * CH * 128 + (size_t)j * 128 + dvb + cc];
    }
    __syncthreads();

    const int tx = tid & 15, ty = tid >> 4;
    const int c0 = tx * 4, i0 = ty * 4;
    float acc[4][4] = {{0}};
    for (int j4 = 0; j4 < 16; ++j4) {
        float uv[4][4];
#pragma unroll
        for (int s = 0; s < 4; ++s) {
            float4 u4 = *(const float4*)&Ush[(j4 * 4 + s) * 68 + c0];
            uv[s][0] = u4.x; uv[s][1] = u4.y; uv[s][2] = u4.z; uv[s][3] = u4.w;
        }
#pragma unroll
        for (int r = 0; r < 4; ++r) {
            float4 m4 = *(const float4*)&Msh[(i0 + r) * 68 + j4 * 4];
            const float mv[4] = {m4.x, m4.y, m4.z, m4.w};
#pragma unroll
            for (int s = 0; s < 4; ++s)
#pragma unroll
                for (int e = 0; e < 4; ++e) acc[r][e] += mv[s] * uv[s][e];
        }
    }
    const float scale = 0.08838834764831845f;
#pragma unroll
    for (int r = 0; r < 4; ++r) {
        float* op = &o[(size_t)(c * CH + i0 + r) * HID + h * DV + dvb + c0];
        float4 prev = *(const float4*)op;
        float4 ov = make_float4(scale * (prev.x + acc[r][0]),
                                scale * (prev.y + acc[r][1]),
                                scale * (prev.z + acc[r][2]),
                                scale * (prev.w + acc[r][3]));
        *(float4*)op = ov;
    }
}

// ---------------------------------------------------------------------------
// Gated RMSNorm: gsil bf16 in, onorm (hi,lo) bf16 out
// ---------------------------------------------------------------------------
__global__ __launch_bounds__(256) void normgate_kernel(const float* __restrict__ o,
                                                       const unsigned short* __restrict__ gsil,
                                                       const float* __restrict__ nw,
                                                       unsigned short* __restrict__ out_hi,
                                                       unsigned short* __restrict__ out_lo) {
    const int gw = (blockIdx.x * 256 + threadIdx.x) >> 6;
    const int lane = threadIdx.x & 63;
    if (gw >= T * NH) return;
    const int t = gw / NH, h = gw % NH;
    const size_t base = (size_t)t * HID + h * DV;
    const float a = o[base + lane];
    const float b = o[base + lane + 64];
    float ss = a * a + b * b;
    ss += __shfl_xor(ss, 1);  ss += __shfl_xor(ss, 2);  ss += __shfl_xor(ss, 4);
    ss += __shfl_xor(ss, 8);  ss += __shfl_xor(ss, 16); ss += __shfl_xor(ss, 32);
    const float r = rsqrtf(ss * (1.0f / 128.0f) + 1e-5f);
    float va = a * r * nw[lane]      * bf2f(gsil[base + lane]);
    float vb = b * r * nw[lane + 64] * bf2f(gsil[base + lane + 64]);
    unsigned short ha = f2bf(va), hb = f2bf(vb);
    out_hi[base + lane]      = ha;  out_lo[base + lane]      = f2bf(va - bf2f(ha));
    out_hi[base + lane + 64] = hb;  out_lo[base + lane + 64] = f2bf(vb - bf2f(hb));
}

// ---------------------------------------------------------------------------
extern "C" void kernel_launch(void* const* d_in, const int* in_sizes, int n_in,
                              void* d_out, int out_size, void* d_ws, size_t ws_size,
                              hipStream_t stream) {
    const float* hs      = (const float*)d_in[0];
    const float* Wq      = (const float*)d_in[1];
    const float* Wk      = (const float*)d_in[2];
    const float* Wv      = (const float*)d_in[3];
    const float* Wb      = (const float*)d_in[4];
    const float* Wa      = (const float*)d_in[5];
    const float* A_log   = (const float*)d_in[6];
    const float* dt_bias = (const float*)d_in[7];
    const float* Wg1     = (const float*)d_in[8];
    const float* Wg2     = (const float*)d_in[9];
    const float* Wgate   = (const float*)d_in[10];
    const float* norm_w  = (const float*)d_in[11];
    const float* Wo      = (const float*)d_in[12];

    float* ws = (float*)d_ws;
    // ---- layout (floats), end = 24,526,848 f = 98.1 MB ----
    float* q    = ws;                                        // later WoTh/WoTl
    float* kbuf = ws + 3145728;
    float* vpre = ws + 6291456;                              // later onh/onl
    float* vbuf = ws + 9437184;                              // early hsbh/hsbl
    unsigned short* gsil = (unsigned short*)(ws + 12582912); // [ ,14155776)
    // region B [14155776, 22020096):
    unsigned short* WTAfh = (unsigned short*)(ws + 14155776); // 4864x1536 fp16 = 3,735,552 f -> 17,891,328
    unsigned short* WTBh  = (unsigned short*)(ws + 17891328); // 1664x1536 bf16 -> 19,169,280
    unsigned short* WTBl  = (unsigned short*)(ws + 19169280); // -> 20,447,232
    unsigned short* wcv   = (unsigned short*)(ws + 14155776); // 2048x6144 bf16 (after GEMMs)
    float* X1g  = ws + 14155776;                             // after conv
    float* X2g  = ws + 17301504;
    float* Mg   = ws + 20447232;                             // -> 22,020,096
    // region C persistents [22044672, ...): no overlaps
    unsigned short* WG2h  = (unsigned short*)(ws + 22044672); // 6144x192 fp16 = 589,824 f -> 22,634,496
    unsigned short* hsh   = (unsigned short*)(ws + 22634496); // 2048x1536 fp16 = 1,572,864 f -> 24,207,360
    unsigned short* w1h16 = (unsigned short*)(ws + 24207360); // 2048x192 fp16 = 196,608 f -> 24,403,968
    float* bgraw = ws + 24403968;                             // 49,152 f -> 24,453,120
    float* beta  = ws + 24453120;                             // 24,576 f
    float* g     = ws + 24477696;                             // 24,576 f
    float* csg   = ws + 24502272;                             // 24,576 f -> 24,526,848
    // overlays
    unsigned short* hsbh = (unsigned short*)(ws + 9437184);
    unsigned short* hsbl = (unsigned short*)(ws + 11010048);
    unsigned short* WoTh = (unsigned short*)(ws);
    unsigned short* WoTl = (unsigned short*)(ws + 1179648);
    unsigned short* onh  = (unsigned short*)(ws + 6291456);
    unsigned short* onl  = (unsigned short*)(ws + 7864320);

    const dim3 blk(256);
    const dim3 blkT(32, 8);

    // P0: hs -> bf16 hi/lo + fp16; weights: A-batch fp16, B-batch bf16 split.
    splitcast3_kernel<<<3072, blk, 0, stream>>>(hs, hsbh, hsbl, hsh, (T * HID) / 4);
    transcasth_kernel<<<dim3(48, 48), blkT, 0, stream>>>(Wq,    WTAfh,               1536, 1536);
    transcasth_kernel<<<dim3(48, 48), blkT, 0, stream>>>(Wv,    WTAfh + 1536 * 1536, 1536, 1536);
    transcasth_kernel<<<dim3(48, 48), blkT, 0, stream>>>(Wgate, WTAfh + 3072 * 1536, 1536, 1536);
    transcasth_kernel<<<dim3(6, 48),  blkT, 0, stream>>>(Wg1,   WTAfh + 4608 * 1536, 1536, 192);
    transsplit_kernel<<<dim3(48, 48), blkT, 0, stream>>>(Wk, WTBh,               WTBl,               1536, 1536);
    transsplit_kernel<<<dim3(1, 48),  blkT, 0, stream>>>(Wb, WTBh + 1536 * 1536, WTBl + 1536 * 1536, 1536, 12);
    transsplit_kernel<<<dim3(1, 48),  blkT, 0, stream>>>(Wa, WTBh + 1548 * 1536, WTBl + 1548 * 1536, 1536, 12);
    transcasth_kernel<<<dim3(192, 6), blkT, 0, stream>>>(Wg2, WG2h, 192, 6144);

    // P1: GEMM-A (single fp16): q|v|gate|w1
    mgemm<1, 0><<<dim3(38, 16), blk, 0, stream>>>(hsh, nullptr, WTAfh, nullptr, 1536, 4864,
        nullptr, nullptr, q, vpre, nullptr, gsil, w1h16, nullptr);
    //     GEMM-B (3-term bf16): k|bg
    mgemm<2, 1><<<dim3(13, 16), blk, 0, stream>>>(hsbh, hsbl, WTBh, WTBl, 1536, 1664,
        nullptr, nullptr, nullptr, nullptr, kbuf, nullptr, nullptr, bgraw);
    bg2_kernel<<<192, blk, 0, stream>>>(bgraw, A_log, dt_bias, beta, g);

    // P2: conv weights GEMM (single fp16, bf16 out) + conv
    mgemm<3, 0><<<dim3(48, 16), blk, 0, stream>>>(w1h16, nullptr, WG2h, nullptr, 192, 6144,
        nullptr, wcv, nullptr, nullptr, nullptr, nullptr, nullptr, nullptr);
    conv_kernel<<<(T * HID) / 256, blk, 0, stream>>>(vpre, wcv, vbuf);

    // P3: chunked delta rule (verified R8)
    chunkloc_kernel<<<dim3(NC, NH), blk, 0, stream>>>(q, kbuf, vbuf, g, beta,
                                                      X1g, X2g, Mg, csg);
    state_kernel<<<dim3(NH, 8), blk, 0, stream>>>(kbuf, q, X1g, X2g, csg, vbuf);
    transsplit_kernel<<<dim3(48, 48), blkT, 0, stream>>>(Wo, WoTh, WoTl, 1536, 1536);
    outk_kernel<<<dim3(NC, NH, 2), blk, 0, stream>>>(X1g, Mg, vbuf);

    // P4: norm + output GEMM (3-term bf16)
    normgate_kernel<<<6144, blk, 0, stream>>>(vbuf, gsil, norm_w, onh, onl);
    mgemm<0, 1><<<dim3(12, 16), blk, 0, stream>>>(onh, onl, WoTh, WoTl, 1536, 1536,
        (float*)d_out, nullptr, nullptr, nullptr, nullptr, nullptr, nullptr, nullptr);
}

// Round 13
// 603.895 us; speedup vs baseline: 1.7568x; 1.1272x over previous
//
#include <hip/hip_runtime.h>
#include <hip/hip_bf16.h>
#include <math.h>

#define T     2048
#define HID   1536
#define NH    12
#define DK    128
#define DV    128
#define CONVK 4
#define CH    64
#define NC    32

typedef __attribute__((ext_vector_type(8))) short bf16x8;
typedef __attribute__((ext_vector_type(8))) _Float16 fp16x8;
typedef __attribute__((ext_vector_type(4))) float floatx4;

__device__ __forceinline__ float siluf(float x) {
    return x / (1.0f + __expf(-x));
}
__device__ __forceinline__ unsigned short f2bf(float f) {
    union { __hip_bfloat16 b; unsigned short u; } cv;
    cv.b = __float2bfloat16(f);
    return cv.u;
}
__device__ __forceinline__ float bf2f(unsigned short u) {
    union { unsigned int u; float f; } cv;
    cv.u = ((unsigned int)u) << 16;
    return cv.f;
}
__device__ __forceinline__ unsigned short f2h(float f) {
    union { _Float16 h; unsigned short u; } cv;
    cv.h = (_Float16)f;
    return cv.u;
}
__device__ __forceinline__ void gl_lds16(const void* g, void* l) {
    __builtin_amdgcn_global_load_lds(
        (const __attribute__((address_space(1))) void*)g,
        (__attribute__((address_space(3))) void*)l, 16, 0, 0);
}
// split 8 fp32 -> hi/lo bf16, write as 2x ushort4 each
__device__ __forceinline__ void split8_store(const float* xv,
                                             unsigned short* dh, unsigned short* dl) {
    ushort4 h0, h1, l0, l1;
    h0.x = f2bf(xv[0]); l0.x = f2bf(xv[0] - bf2f(h0.x));
    h0.y = f2bf(xv[1]); l0.y = f2bf(xv[1] - bf2f(h0.y));
    h0.z = f2bf(xv[2]); l0.z = f2bf(xv[2] - bf2f(h0.z));
    h0.w = f2bf(xv[3]); l0.w = f2bf(xv[3] - bf2f(h0.w));
    h1.x = f2bf(xv[4]); l1.x = f2bf(xv[4] - bf2f(h1.x));
    h1.y = f2bf(xv[5]); l1.y = f2bf(xv[5] - bf2f(h1.y));
    h1.z = f2bf(xv[6]); l1.z = f2bf(xv[6] - bf2f(h1.z));
    h1.w = f2bf(xv[7]); l1.w = f2bf(xv[7] - bf2f(h1.w));
    *(ushort4*)dh = h0; *(ushort4*)(dh + 4) = h1;
    *(ushort4*)dl = l0; *(ushort4*)(dl + 4) = l1;
}

// ---------------------------------------------------------------------------
// hs: fp32 -> bf16 hi, bf16 lo, fp16  (one pass)
// ---------------------------------------------------------------------------
__global__ __launch_bounds__(256) void splitcast3_kernel(const float* __restrict__ s,
                                                         unsigned short* __restrict__ hi,
                                                         unsigned short* __restrict__ lo,
                                                         unsigned short* __restrict__ h16,
                                                         int n4) {
    int i = blockIdx.x * 256 + threadIdx.x;
    if (i >= n4) return;
    float4 x = ((const float4*)s)[i];
    ushort4 h, l, f;
    h.x = f2bf(x.x); l.x = f2bf(x.x - bf2f(h.x)); f.x = f2h(x.x);
    h.y = f2bf(x.y); l.y = f2bf(x.y - bf2f(h.y)); f.y = f2h(x.y);
    h.z = f2bf(x.z); l.z = f2bf(x.z - bf2f(h.z)); f.z = f2h(x.z);
    h.w = f2bf(x.w); l.w = f2bf(x.w - bf2f(h.w)); f.w = f2h(x.w);
    ((ushort4*)hi)[i] = h;
    ((ushort4*)lo)[i] = l;
    ((ushort4*)h16)[i] = f;
}

// ---------------------------------------------------------------------------
// transpose + split: src (K x N fp32) -> hi/lo (N x K bf16). K%32==0.
// ---------------------------------------------------------------------------
__global__ __launch_bounds__(256) void transsplit_kernel(const float* __restrict__ src,
                                                         unsigned short* __restrict__ hi,
                                                         unsigned short* __restrict__ lo,
                                                         int K, int N) {
    __shared__ float tile[32][33];
    const int k0 = blockIdx.y * 32, n0 = blockIdx.x * 32;
    const int tx = threadIdx.x, ty = threadIdx.y;
#pragma unroll
    for (int r = 0; r < 4; ++r) {
        int kk = k0 + ty + 8 * r, nn = n0 + tx;
        tile[ty + 8 * r][tx] = (nn < N) ? src[(size_t)kk * N + nn] : 0.0f;
    }
    __syncthreads();
#pragma unroll
    for (int r = 0; r < 4; ++r) {
        int nn = n0 + ty + 8 * r, kk = k0 + tx;
        if (nn < N) {
            float x = tile[tx][ty + 8 * r];
            unsigned short h = f2bf(x);
            hi[(size_t)nn * K + kk] = h;
            lo[(size_t)nn * K + kk] = f2bf(x - bf2f(h));
        }
    }
}

// ---------------------------------------------------------------------------
// transpose + cast fp16: src (K x N fp32) -> dst (N x K fp16).
// ---------------------------------------------------------------------------
__global__ __launch_bounds__(256) void transcasth_kernel(const float* __restrict__ src,
                                                         unsigned short* __restrict__ dst,
                                                         int K, int N) {
    __shared__ float tile[32][33];
    const int k0 = blockIdx.y * 32, n0 = blockIdx.x * 32;
    const int tx = threadIdx.x, ty = threadIdx.y;
#pragma unroll
    for (int r = 0; r < 4; ++r) {
        int kk = k0 + ty + 8 * r, nn = n0 + tx;
        tile[ty + 8 * r][tx] = (nn < N) ? src[(size_t)kk * N + nn] : 0.0f;
    }
    __syncthreads();
#pragma unroll
    for (int r = 0; r < 4; ++r) {
        int nn = n0 + ty + 8 * r, kk = k0 + tx;
        if (nn < N) dst[(size_t)nn * K + kk] = f2h(tile[tx][ty + 8 * r]);
    }
}

// ---------------------------------------------------------------------------
// MFMA GEMM, 128x128 tile, BK=32, 256 thr. A: M x K, B: N x K.
// MODE 0: single fp16.  MODE 1: 3-term bf16 split (eff. fp32).
// EPI 0: C fp32.  EPI 1: q|v|gate|w1(fp16).  EPI 2: k|bg.  EPI 3: Cb bf16.
// ---------------------------------------------------------------------------
template<int EPI, int MODE>
__global__ __launch_bounds__(256)
void mgemm(const unsigned short* __restrict__ Ah, const unsigned short* __restrict__ Al,
           const unsigned short* __restrict__ Bh, const unsigned short* __restrict__ Bl,
           int K, int N, float* __restrict__ C, unsigned short* __restrict__ Cb,
           float* __restrict__ qf, float* __restrict__ vf, float* __restrict__ kf,
           unsigned short* __restrict__ gsilb, unsigned short* __restrict__ w1h16,
           float* __restrict__ bgraw)
{
    __shared__ unsigned short AsH[4096], BsH[4096];
    __shared__ unsigned short AsL[MODE ? 4096 : 4], BsL[MODE ? 4096 : 4];
    const int tid = threadIdx.x;
    const int wave = tid >> 6, lane = tid & 63;
    const int wr = wave >> 1, wc = wave & 1;
    const int lm = lane & 15, lq = lane >> 4;
    const int rowBase = blockIdx.y * 128, colBase = blockIdx.x * 128;

    floatx4 acc[4][4];
#pragma unroll
    for (int i = 0; i < 4; ++i)
#pragma unroll
        for (int j = 0; j < 4; ++j) acc[i][j] = (floatx4){0.f, 0.f, 0.f, 0.f};

    const int mt0 = wave * 2, mt1 = wave * 2 + 1;
    const size_t aOff0 = (size_t)(rowBase + mt0 * 16 + lm) * K + lq * 8;
    const size_t aOff1 = (size_t)(rowBase + mt1 * 16 + lm) * K + lq * 8;
    const size_t bOff0 = (size_t)(colBase + mt0 * 16 + lm) * K + lq * 8;
    const size_t bOff1 = (size_t)(colBase + mt1 * 16 + lm) * K + lq * 8;

    for (int k0 = 0; k0 < K; k0 += 32) {
        gl_lds16(Ah + aOff0 + k0, &AsH[mt0 * 512]);
        gl_lds16(Ah + aOff1 + k0, &AsH[mt1 * 512]);
        gl_lds16(Bh + bOff0 + k0, &BsH[mt0 * 512]);
        gl_lds16(Bh + bOff1 + k0, &BsH[mt1 * 512]);
        if (MODE) {
            gl_lds16(Al + aOff0 + k0, &AsL[mt0 * 512]);
            gl_lds16(Al + aOff1 + k0, &AsL[mt1 * 512]);
            gl_lds16(Bl + bOff0 + k0, &BsL[mt0 * 512]);
            gl_lds16(Bl + bOff1 + k0, &BsL[mt1 * 512]);
        }
        __syncthreads();
        if (MODE == 0) {
            fp16x8 a[4], b[4];
#pragma unroll
            for (int i = 0; i < 4; ++i) {
                a[i] = *(const fp16x8*)&AsH[(wr * 4 + i) * 512 + lane * 8];
                b[i] = *(const fp16x8*)&BsH[(wc * 4 + i) * 512 + lane * 8];
            }
#pragma unroll
            for (int mi = 0; mi < 4; ++mi)
#pragma unroll
                for (int ni = 0; ni < 4; ++ni)
                    acc[mi][ni] = __builtin_amdgcn_mfma_f32_16x16x32_f16(
                        a[mi], b[ni], acc[mi][ni], 0, 0, 0);
        } else {
            bf16x8 ah[4], al[4], bh[4], bl[4];
#pragma unroll
            for (int i = 0; i < 4; ++i) {
                ah[i] = *(const bf16x8*)&AsH[(wr * 4 + i) * 512 + lane * 8];
                bh[i] = *(const bf16x8*)&BsH[(wc * 4 + i) * 512 + lane * 8];
                al[i] = *(const bf16x8*)&AsL[(wr * 4 + i) * 512 + lane * 8];
                bl[i] = *(const bf16x8*)&BsL[(wc * 4 + i) * 512 + lane * 8];
            }
#pragma unroll
            for (int mi = 0; mi < 4; ++mi)
#pragma unroll
                for (int ni = 0; ni < 4; ++ni) {
                    acc[mi][ni] = __builtin_amdgcn_mfma_f32_16x16x32_bf16(
                        ah[mi], bh[ni], acc[mi][ni], 0, 0, 0);
                    acc[mi][ni] = __builtin_amdgcn_mfma_f32_16x16x32_bf16(
                        al[mi], bh[ni], acc[mi][ni], 0, 0, 0);
                    acc[mi][ni] = __builtin_amdgcn_mfma_f32_16x16x32_bf16(
                        ah[mi], bl[ni], acc[mi][ni], 0, 0, 0);
                }
        }
        __syncthreads();
    }

#pragma unroll
    for (int mi = 0; mi < 4; ++mi)
#pragma unroll
        for (int ni = 0; ni < 4; ++ni) {
            const int col = colBase + wc * 64 + ni * 16 + lm;
#pragma unroll
            for (int r = 0; r < 4; ++r) {
                const int row = rowBase + wr * 64 + mi * 16 + lq * 4 + r;
                const float x = acc[mi][ni][r];
                if (EPI == 0) {
                    C[(size_t)row * N + col] = x;
                } else if (EPI == 3) {
                    Cb[(size_t)row * N + col] = f2bf(x);
                } else if (EPI == 1) {
                    if (col < 1536)       qf[(size_t)row * 1536 + col] = siluf(x);
                    else if (col < 3072)  vf[(size_t)row * 1536 + col - 1536] = x;
                    else if (col < 4608)  gsilb[(size_t)row * 1536 + col - 3072] = f2bf(siluf(x));
                    else if (col < 4800)  w1h16[(size_t)row * 192 + col - 4608] = f2h(siluf(x));
                } else {  // EPI == 2: k | bg
                    if (col < 1536)       kf[(size_t)row * 1536 + col] = siluf(x);
                    else if (col < 1560)  bgraw[(size_t)row * 24 + col - 1536] = x;
                }
            }
        }
}

// ---------------------------------------------------------------------------
__global__ __launch_bounds__(256) void bg2_kernel(const float* __restrict__ bgraw,
                                                  const float* __restrict__ A_log,
                                                  const float* __restrict__ dt_bias,
                                                  float* __restrict__ beta,
                                                  float* __restrict__ g) {
    int idx = blockIdx.x * 256 + threadIdx.x;
    if (idx >= T * 24) return;
    int t = idx / 24, c = idx % 24;
    float x = bgraw[idx];
    if (c < 12) {
        beta[t * NH + c] = 1.0f / (1.0f + __expf(-x));
    } else {
        int h = c - 12;
        float y = x + dt_bias[h];
        float sp = (y > 20.0f) ? y : log1pf(__expf(y));
        g[t * NH + h] = -__expf(A_log[h]) * sp;
    }
}

// ---------------------------------------------------------------------------
__global__ __launch_bounds__(256) void conv_kernel(const float* __restrict__ vpre,
                                                   const unsigned short* __restrict__ w,
                                                   float* __restrict__ v) {
    const int idx = blockIdx.x * 256 + threadIdx.x;
    if (idx >= T * HID) return;
    const int t = idx / HID, d = idx % HID;
    const ushort4 wv = *(const ushort4*)(w + (size_t)t * (HID * CONVK) + d * 4);
    const float w4[4] = { bf2f(wv.x), bf2f(wv.y), bf2f(wv.z), bf2f(wv.w) };
    float acc = 0.0f;
#pragma unroll
    for (int i = 0; i < CONVK; i++) {
        const int ts = t - (CONVK - 1) + i;
        if (ts >= 0) acc += vpre[(size_t)ts * HID + d] * w4[i];
    }
    v[idx] = siluf(acc);
}

// ---------------------------------------------------------------------------
// prep: tile q and k into MFMA-fragment-ordered bf16 hi/lo global buffers.
// grid (NC, NH), 256 thr.
// Q: A-op [i][dk], chunk = mt*4+ks (mt 0..3 over i, ks 0..3 over dk), lane l
//    holds row mt*16+(l&15), cols ks*32+(l>>4)*8 .. +7, at chunk*512 + l*8.
// K: [dk][i], chunk = mt*2+ks (mt 0..7 over dk, ks 0..1 over i).
// ---------------------------------------------------------------------------
__global__ __launch_bounds__(256) void prep_kernel(
    const float* __restrict__ q, const float* __restrict__ k,
    unsigned short* __restrict__ Qth, unsigned short* __restrict__ Qtl,
    unsigned short* __restrict__ Kth, unsigned short* __restrict__ Ktl)
{
    __shared__ float KT[128 * 68];
    const int c = blockIdx.x, h = blockIdx.y;
    const int tid = threadIdx.x;
    const size_t tb = (size_t)(h * NC + c) * 8192;

    // stage K^T fp32 into LDS
    {
        const int li = tid >> 2, lq4 = tid & 3;
        const float* src = k + (size_t)(c * CH + li) * HID + h * DK + lq4 * 32;
#pragma unroll
        for (int f = 0; f < 8; ++f) {
            float4 x = *(const float4*)(src + f * 4);
            int d0 = lq4 * 32 + f * 4;
            KT[(d0 + 0) * 68 + li] = x.x; KT[(d0 + 1) * 68 + li] = x.y;
            KT[(d0 + 2) * 68 + li] = x.z; KT[(d0 + 3) * 68 + li] = x.w;
        }
    }

    // Q tiled emission (direct from global)
#pragma unroll
    for (int e = 0; e < 4; ++e) {
        int u = e * 256 + tid;
        int ch = u >> 6, l = u & 63;
        int i = (ch >> 2) * 16 + (l & 15);
        int dbase = (ch & 3) * 32 + (l >> 4) * 8;
        const float* src = q + (size_t)(c * CH + i) * HID + h * DK + dbase;
        float4 a = *(const float4*)src, b = *(const float4*)(src + 4);
        float xv[8] = {a.x, a.y, a.z, a.w, b.x, b.y, b.z, b.w};
        split8_store(xv, &Qth[tb + ch * 512 + l * 8], &Qtl[tb + ch * 512 + l * 8]);
    }
    __syncthreads();

    // K tiled emission (from LDS transpose)
#pragma unroll
    for (int e = 0; e < 4; ++e) {
        int u = e * 256 + tid;
        int ch = u >> 6, l = u & 63;
        int dk = (ch >> 1) * 16 + (l & 15);
        int ibase = (ch & 1) * 32 + (l >> 4) * 8;
        float4 a = *(const float4*)&KT[dk * 68 + ibase];
        float4 b = *(const float4*)&KT[dk * 68 + ibase + 4];
        float xv[8] = {a.x, a.y, a.z, a.w, b.x, b.y, b.z, b.w};
        split8_store(xv, &Kth[tb + ch * 512 + l * 8], &Ktl[tb + ch * 512 + l * 8]);
    }
}

// ---------------------------------------------------------------------------
// D1: chunk-local WY precompute — MFMA version; X2 now emitted as tiled
// (negated) bf16 hi/lo (A-op layout) instead of fp32.
// ---------------------------------------------------------------------------
__global__ __launch_bounds__(256, 1) void chunkloc_kernel(
    const float* __restrict__ q, const float* __restrict__ k, const float* __restrict__ v,
    const float* __restrict__ g, const float* __restrict__ beta,
    float* __restrict__ X1g,
    unsigned short* __restrict__ X2th, unsigned short* __restrict__ X2tl,
    float* __restrict__ Mg, float* __restrict__ csg)
{
    __shared__ unsigned short KhS[64 * 136], KlS[64 * 136];
    __shared__ unsigned short QhS[64 * 136], QlS[64 * 136];
    __shared__ float KT[128 * 68];
    __shared__ float Vs[64 * 132];
    __shared__ float As[64 * 68];
    __shared__ float cs[64], sb[64], sbb[64];

    const int c = blockIdx.x, h = blockIdx.y;
    const int tid = threadIdx.x;
    const int wave = tid >> 6, lane = tid & 63;
    const int lm = lane & 15, lq = lane >> 4;
    const int li = tid >> 2, lq4 = tid & 3;
    const size_t rowbase = (size_t)(c * CH) * HID + h * DK;

    {
        const float* ksrc = k + rowbase + (size_t)li * HID + lq4 * 32;
        const float* qsrc = q + rowbase + (size_t)li * HID + lq4 * 32;
        const float* vsrc = v + (size_t)(c * CH + li) * HID + h * DV + lq4 * 32;
#pragma unroll
        for (int f = 0; f < 8; ++f) {
            float4 kx = *(const float4*)(ksrc + f * 4);
            float4 qx = *(const float4*)(qsrc + f * 4);
            float4 vx = *(const float4*)(vsrc + f * 4);
            const int d0 = lq4 * 32 + f * 4;
            {
                ushort4 hh, ll;
                hh.x = f2bf(kx.x); ll.x = f2bf(kx.x - bf2f(hh.x));
                hh.y = f2bf(kx.y); ll.y = f2bf(kx.y - bf2f(hh.y));
                hh.z = f2bf(kx.z); ll.z = f2bf(kx.z - bf2f(hh.z));
                hh.w = f2bf(kx.w); ll.w = f2bf(kx.w - bf2f(hh.w));
                *(ushort4*)&KhS[li * 136 + d0] = hh;
                *(ushort4*)&KlS[li * 136 + d0] = ll;
            }
            {
                ushort4 hh, ll;
                hh.x = f2bf(qx.x); ll.x = f2bf(qx.x - bf2f(hh.x));
                hh.y = f2bf(qx.y); ll.y = f2bf(qx.y - bf2f(hh.y));
                hh.z = f2bf(qx.z); ll.z = f2bf(qx.z - bf2f(hh.z));
                hh.w = f2bf(qx.w); ll.w = f2bf(qx.w - bf2f(hh.w));
                *(ushort4*)&QhS[li * 136 + d0] = hh;
                *(ushort4*)&QlS[li * 136 + d0] = ll;
            }
            KT[(d0 + 0) * 68 + li] = kx.x;
            KT[(d0 + 1) * 68 + li] = kx.y;
            KT[(d0 + 2) * 68 + li] = kx.z;
            KT[(d0 + 3) * 68 + li] = kx.w;
            *(float4*)&Vs[li * 132 + d0] = vx;
        }
    }
    if (tid < 64) {
        float gv = g[(c * CH + tid) * NH + h];
        float bv = beta[(c * CH + tid) * NH + h];
        float csv = gv;
#pragma unroll
        for (int off = 1; off < 64; off <<= 1) {
            float n = __shfl_up(csv, off);
            if (tid >= off) csv += n;
        }
        cs[tid] = csv; sb[tid] = bv; sbb[tid] = bv * __expf(csv);
    }
    __syncthreads();

    {
        const int ti = wave;
#pragma unroll
        for (int tj = 0; tj < 4; ++tj) {
            floatx4 acc = (floatx4){0.f, 0.f, 0.f, 0.f};
#pragma unroll
            for (int ks = 0; ks < 4; ++ks) {
                bf16x8 a_h = *(const bf16x8*)&KhS[(ti * 16 + lm) * 136 + ks * 32 + lq * 8];
                bf16x8 a_l = *(const bf16x8*)&KlS[(ti * 16 + lm) * 136 + ks * 32 + lq * 8];
                bf16x8 b_h = *(const bf16x8*)&KhS[(tj * 16 + lm) * 136 + ks * 32 + lq * 8];
                bf16x8 b_l = *(const bf16x8*)&KlS[(tj * 16 + lm) * 136 + ks * 32 + lq * 8];
                acc = __builtin_amdgcn_mfma_f32_16x16x32_bf16(a_h, b_h, acc, 0, 0, 0);
                acc = __builtin_amdgcn_mfma_f32_16x16x32_bf16(a_h, b_l, acc, 0, 0, 0);
                acc = __builtin_amdgcn_mfma_f32_16x16x32_bf16(a_l, b_h, acc, 0, 0, 0);
            }
#pragma unroll
            for (int r = 0; r < 4; ++r) {
                const int i = ti * 16 + lq * 4 + r, j = tj * 16 + lm;
                As[i * 68 + j] = (j < i) ? sb[i] * __expf(cs[i] - cs[j]) * acc[r] : 0.0f;
            }
        }
        const size_t mbase = (size_t)(h * NC + c) * CH * CH;
#pragma unroll
        for (int tj = 0; tj < 4; ++tj) {
            floatx4 acc = (floatx4){0.f, 0.f, 0.f, 0.f};
#pragma unroll
            for (int ks = 0; ks < 4; ++ks) {
                bf16x8 a_h = *(const bf16x8*)&QhS[(ti * 16 + lm) * 136 + ks * 32 + lq * 8];
                bf16x8 a_l = *(const bf16x8*)&QlS[(ti * 16 + lm) * 136 + ks * 32 + lq * 8];
                bf16x8 b_h = *(const bf16x8*)&KhS[(tj * 16 + lm) * 136 + ks * 32 + lq * 8];
                bf16x8 b_l = *(const bf16x8*)&KlS[(tj * 16 + lm) * 136 + ks * 32 + lq * 8];
                acc = __builtin_amdgcn_mfma_f32_16x16x32_bf16(a_h, b_h, acc, 0, 0, 0);
                acc = __builtin_amdgcn_mfma_f32_16x16x32_bf16(a_h, b_l, acc, 0, 0, 0);
                acc = __builtin_amdgcn_mfma_f32_16x16x32_bf16(a_l, b_h, acc, 0, 0, 0);
            }
#pragma unroll
            for (int r = 0; r < 4; ++r) {
                const int i = ti * 16 + lq * 4 + r, j = tj * 16 + lm;
                Mg[mbase + (size_t)i * 64 + j] =
                    (j <= i) ? __expf(cs[i] - cs[j]) * acc[r] : 0.0f;
            }
        }
    }

    float xc[64];
    const int col = tid;
    if (col < 128) {
#pragma unroll
        for (int i = 0; i < 64; ++i) xc[i] = sb[i] * Vs[i * 132 + col];
    } else {
        const int dcol = col - 128;
#pragma unroll
        for (int i4 = 0; i4 < 16; ++i4) {
            float4 kq = *(const float4*)&KT[dcol * 68 + i4 * 4];
            xc[i4 * 4 + 0] = sbb[i4 * 4 + 0] * kq.x;
            xc[i4 * 4 + 1] = sbb[i4 * 4 + 1] * kq.y;
            xc[i4 * 4 + 2] = sbb[i4 * 4 + 2] * kq.z;
            xc[i4 * 4 + 3] = sbb[i4 * 4 + 3] * kq.w;
        }
    }
    __syncthreads();

#pragma unroll
    for (int i = 1; i < 64; ++i) {
        float a = xc[i];
#pragma unroll
        for (int j4 = 0; j4 < (i + 3) / 4; ++j4) {
            float4 a4 = *(const float4*)&As[i * 68 + j4 * 4];
            a -= a4.x * xc[j4 * 4 + 0] + a4.y * xc[j4 * 4 + 1]
               + a4.z * xc[j4 * 4 + 2] + a4.w * xc[j4 * 4 + 3];
        }
        xc[i] = a;
    }

    // X1 fp32; X2 columns -> Vs for transpose
    {
        const size_t xbase = (size_t)(h * NC + c) * CH * 128;
        if (col < 128) {
            for (int i = 0; i < 64; ++i) X1g[xbase + (size_t)i * 128 + col] = xc[i];
        } else {
            for (int i = 0; i < 64; ++i) Vs[i * 132 + (col - 128)] = xc[i];
        }
    }
    if (tid < 64) csg[(size_t)(h * NC + c) * CH + tid] = cs[tid];
    __syncthreads();

    // tiled (negated) X2 emission
    {
        const size_t tb = (size_t)(h * NC + c) * 8192;
#pragma unroll
        for (int e = 0; e < 4; ++e) {
            int u = e * 256 + tid;
            int ch = u >> 6, l = u & 63;
            int i = (ch >> 2) * 16 + (l & 15);
            int dbase = (ch & 3) * 32 + (l >> 4) * 8;
            float4 a = *(const float4*)&Vs[i * 132 + dbase];
            float4 b = *(const float4*)&Vs[i * 132 + dbase + 4];
            float xv[8] = {-a.x, -a.y, -a.z, -a.w, -b.x, -b.y, -b.z, -b.w};
            split8_store(xv, &X2th[tb + ch * 512 + l * 8], &X2tl[tb + ch * 512 + l * 8]);
        }
    }
}

// ---------------------------------------------------------------------------
// D2: serial inter-chunk recurrence — MFMA, staging via gl_lds16 from
// pre-tiled buffers (zero in-loop split work). grid (NH, 8).
// ---------------------------------------------------------------------------
__global__ __launch_bounds__(256, 1) void state_kernel(
    const unsigned short* __restrict__ Qth, const unsigned short* __restrict__ Qtl,
    const unsigned short* __restrict__ Kth, const unsigned short* __restrict__ Ktl,
    const unsigned short* __restrict__ X2th, const unsigned short* __restrict__ X2tl,
    float* __restrict__ X1g /* in: X1, out: U */,
    const float* __restrict__ csg, float* __restrict__ o)
{
    __shared__ unsigned short XAh[8192], XAl[8192];   // -X2, A-op tiled
    __shared__ unsigned short QAh[8192], QAl[8192];   //  Q,  A-op tiled
    __shared__ unsigned short KAh[8192], KAl[8192];   //  K^T tiled
    __shared__ unsigned short SBh[16 * 136], SBl[16 * 136];
    __shared__ unsigned short UBh[16 * 72],  UBl[16 * 72];
    __shared__ float St[16 * 132];
    __shared__ float scs[64];

    const int h = blockIdx.x, db = blockIdx.y;
    const int tid = threadIdx.x;
    const int wave = tid >> 6, lane = tid & 63;
    const int lm = lane & 15, lq = lane >> 4;

    for (int idx = tid; idx < 16 * 132; idx += 256) St[idx] = 0.0f;
    for (int idx = tid; idx < 16 * 136; idx += 256) { SBh[idx] = 0; SBl[idx] = 0; }
    __syncthreads();

    for (int c = 0; c < NC; ++c) {
        const size_t hc = (size_t)(h * NC + c);
        const size_t xb = hc * CH * 128;
        const size_t tb = hc * 8192 + (size_t)lane * 8;

        // ---- phase 1: async staging ----
        if (tid < 64) scs[tid] = csg[hc * CH + tid];
#pragma unroll
        for (int i2 = 0; i2 < 4; ++i2) {
            const int ch = wave * 4 + i2;
            gl_lds16(Qth  + tb + ch * 512, &QAh[ch * 512]);
            gl_lds16(Qtl  + tb + ch * 512, &QAl[ch * 512]);
            gl_lds16(X2th + tb + ch * 512, &XAh[ch * 512]);
            gl_lds16(X2tl + tb + ch * 512, &XAl[ch * 512]);
            gl_lds16(Kth  + tb + ch * 512, &KAh[ch * 512]);
            gl_lds16(Ktl  + tb + ch * 512, &KAl[ch * 512]);
        }
        __syncthreads();

        // ---- phase 2: U + o1 via MFMA ----
        {
            const int mw = wave;
            float x1r[4];
#pragma unroll
            for (int r = 0; r < 4; ++r)
                x1r[r] = X1g[xb + (size_t)(mw * 16 + lq * 4 + r) * 128 + db * 16 + lm];
            floatx4 accU = (floatx4){0.f, 0.f, 0.f, 0.f};
            floatx4 accO = (floatx4){0.f, 0.f, 0.f, 0.f};
#pragma unroll
            for (int ks = 0; ks < 4; ++ks) {
                bf16x8 xh = *(const bf16x8*)&XAh[(mw * 4 + ks) * 512 + lane * 8];
                bf16x8 xl = *(const bf16x8*)&XAl[(mw * 4 + ks) * 512 + lane * 8];
                bf16x8 qh = *(const bf16x8*)&QAh[(mw * 4 + ks) * 512 + lane * 8];
                bf16x8 ql = *(const bf16x8*)&QAl[(mw * 4 + ks) * 512 + lane * 8];
                bf16x8 sh = *(const bf16x8*)&SBh[lm * 136 + ks * 32 + lq * 8];
                bf16x8 sl = *(const bf16x8*)&SBl[lm * 136 + ks * 32 + lq * 8];
                accU = __builtin_amdgcn_mfma_f32_16x16x32_bf16(xh, sh, accU, 0, 0, 0);
                accU = __builtin_amdgcn_mfma_f32_16x16x32_bf16(xh, sl, accU, 0, 0, 0);
                accU = __builtin_amdgcn_mfma_f32_16x16x32_bf16(xl, sh, accU, 0, 0, 0);
                accO = __builtin_amdgcn_mfma_f32_16x16x32_bf16(qh, sh, accO, 0, 0, 0);
                accO = __builtin_amdgcn_mfma_f32_16x16x32_bf16(qh, sl, accO, 0, 0, 0);
                accO = __builtin_amdgcn_mfma_f32_16x16x32_bf16(ql, sh, accO, 0, 0, 0);
            }
            const float cs63 = scs[63];
#pragma unroll
            for (int r = 0; r < 4; ++r) {
                const int row = mw * 16 + lq * 4 + r;
                const float u = accU[r] + x1r[r];
                X1g[xb + (size_t)row * 128 + db * 16 + lm] = u;
                const float up = u * __expf(cs63 - scs[row]);
                unsigned short uh = f2bf(up);
                UBh[lm * 72 + row] = uh;
                UBl[lm * 72 + row] = f2bf(up - bf2f(uh));
                o[(size_t)(c * CH + row) * HID + h * DV + db * 16 + lm] =
                    __expf(scs[row]) * accO[r];
            }
        }
        __syncthreads();

        // ---- phase 3: S = exp(cs63)*S + K^T U' via MFMA ----
        {
            const float bC = __expf(scs[63]);
#pragma unroll
            for (int mt2 = 0; mt2 < 2; ++mt2) {
                const int mt = wave * 2 + mt2;
                floatx4 acc;
#pragma unroll
                for (int r = 0; r < 4; ++r)
                    acc[r] = bC * St[lm * 132 + mt * 16 + lq * 4 + r];
#pragma unroll
                for (int ks = 0; ks < 2; ++ks) {
                    bf16x8 ah = *(const bf16x8*)&KAh[(mt * 2 + ks) * 512 + lane * 8];
                    bf16x8 al = *(const bf16x8*)&KAl[(mt * 2 + ks) * 512 + lane * 8];
                    bf16x8 bh = *(const bf16x8*)&UBh[lm * 72 + ks * 32 + lq * 8];
                    bf16x8 bl = *(const bf16x8*)&UBl[lm * 72 + ks * 32 + lq * 8];
                    acc = __builtin_amdgcn_mfma_f32_16x16x32_bf16(ah, bh, acc, 0, 0, 0);
                    acc = __builtin_amdgcn_mfma_f32_16x16x32_bf16(ah, bl, acc, 0, 0, 0);
                    acc = __builtin_amdgcn_mfma_f32_16x16x32_bf16(al, bh, acc, 0, 0, 0);
                }
#pragma unroll
                for (int r = 0; r < 4; ++r) {
                    const int dk = mt * 16 + lq * 4 + r;
                    const float sv = acc[r];
                    St[lm * 132 + dk] = sv;
                    unsigned short sh = f2bf(sv);
                    SBh[lm * 136 + dk] = sh;
                    SBl[lm * 136 + dk] = f2bf(sv - bf2f(sh));
                }
            }
        }
        __syncthreads();
    }
}

// ---------------------------------------------------------------------------
// D3: o = scale * (o + M U), all fp32 (verified)
// ---------------------------------------------------------------------------
__global__ __launch_bounds__(256) void outk_kernel(
    const float* __restrict__ Ug, const float* __restrict__ Mg,
    float* __restrict__ o)
{
    __shared__ float Msh[64 * 68];
    __shared__ float Ush[64 * 68];

    const int c = blockIdx.x, h = blockIdx.y;
    const int dvb = blockIdx.z * 64;
    const int tid = threadIdx.x;
    const size_t hc = (size_t)(h * NC + c);

    for (int e = 0; e < 16; ++e) {
        int idx = e * 256 + tid;
        Msh[(idx >> 6) * 68 + (idx & 63)] = Mg[hc * CH * CH + idx];
    }
    for (int e = 0; e < 16; ++e) {
        int idx = e * 256 + tid;
        int j = idx >> 6, cc = idx & 63;
        Ush[j * 68 + cc] = Ug[hc * CH * 128 + (size_t)j * 128 + dvb + cc];
    }
    __syncthreads();

    const int tx = tid & 15, ty = tid >> 4;
    const int c0 = tx * 4, i0 = ty * 4;
    float acc[4][4] = {{0}};
    for (int j4 = 0; j4 < 16; ++j4) {
        float uv[4][4];
#pragma unroll
        for (int s = 0; s < 4; ++s) {
            float4 u4 = *(const float4*)&Ush[(j4 * 4 + s) * 68 + c0];
            uv[s][0] = u4.x; uv[s][1] = u4.y; uv[s][2] = u4.z; uv[s][3] = u4.w;
        }
#pragma unroll
        for (int r = 0; r < 4; ++r) {
            float4 m4 = *(const float4*)&Msh[(i0 + r) * 68 + j4 * 4];
            const float mv[4] = {m4.x, m4.y, m4.z, m4.w};
#pragma unroll
            for (int s = 0; s < 4; ++s)
#pragma unroll
                for (int e = 0; e < 4; ++e) acc[r][e] += mv[s] * uv[s][e];
        }
    }
    const float scale = 0.08838834764831845f;
#pragma unroll
    for (int r = 0; r < 4; ++r) {
        float* op = &o[(size_t)(c * CH + i0 + r) * HID + h * DV + dvb + c0];
        float4 prev = *(const float4*)op;
        float4 ov = make_float4(scale * (prev.x + acc[r][0]),
                                scale * (prev.y + acc[r][1]),
                                scale * (prev.z + acc[r][2]),
                                scale * (prev.w + acc[r][3]));
        *(float4*)op = ov;
    }
}

// ---------------------------------------------------------------------------
// Gated RMSNorm: gsil bf16 in, onorm (hi,lo) bf16 out
// ---------------------------------------------------------------------------
__global__ __launch_bounds__(256) void normgate_kernel(const float* __restrict__ o,
                                                       const unsigned short* __restrict__ gsil,
                                                       const float* __restrict__ nw,
                                                       unsigned short* __restrict__ out_hi,
                                                       unsigned short* __restrict__ out_lo) {
    const int gw = (blockIdx.x * 256 + threadIdx.x) >> 6;
    const int lane = threadIdx.x & 63;
    if (gw >= T * NH) return;
    const int t = gw / NH, h = gw % NH;
    const size_t base = (size_t)t * HID + h * DV;
    const float a = o[base + lane];
    const float b = o[base + lane + 64];
    float ss = a * a + b * b;
    ss += __shfl_xor(ss, 1);  ss += __shfl_xor(ss, 2);  ss += __shfl_xor(ss, 4);
    ss += __shfl_xor(ss, 8);  ss += __shfl_xor(ss, 16); ss += __shfl_xor(ss, 32);
    const float r = rsqrtf(ss * (1.0f / 128.0f) + 1e-5f);
    float va = a * r * nw[lane]      * bf2f(gsil[base + lane]);
    float vb = b * r * nw[lane + 64] * bf2f(gsil[base + lane + 64]);
    unsigned short ha = f2bf(va), hb = f2bf(vb);
    out_hi[base + lane]      = ha;  out_lo[base + lane]      = f2bf(va - bf2f(ha));
    out_hi[base + lane + 64] = hb;  out_lo[base + lane + 64] = f2bf(vb - bf2f(hb));
}

// ---------------------------------------------------------------------------
extern "C" void kernel_launch(void* const* d_in, const int* in_sizes, int n_in,
                              void* d_out, int out_size, void* d_ws, size_t ws_size,
                              hipStream_t stream) {
    const float* hs      = (const float*)d_in[0];
    const float* Wq      = (const float*)d_in[1];
    const float* Wk      = (const float*)d_in[2];
    const float* Wv      = (const float*)d_in[3];
    const float* Wb      = (const float*)d_in[4];
    const float* Wa      = (const float*)d_in[5];
    const float* A_log   = (const float*)d_in[6];
    const float* dt_bias = (const float*)d_in[7];
    const float* Wg1     = (const float*)d_in[8];
    const float* Wg2     = (const float*)d_in[9];
    const float* Wgate   = (const float*)d_in[10];
    const float* norm_w  = (const float*)d_in[11];
    const float* Wo      = (const float*)d_in[12];

    float* ws = (float*)d_ws;
    // ---- layout (floats), end = 25,264,128 f = 101.1 MB (<= proven 102.4) ----
    float* q    = ws;                                        // later WoTh/WoTl
    float* kbuf = ws + 3145728;
    float* vpre = ws + 6291456;                              // later Qt, then onh/onl
    float* vbuf = ws + 9437184;                              // early hsbh/hsbl; then v / o
    unsigned short* gsil = (unsigned short*)(ws + 12582912); // [ ,14155776)
    // region B:
    float* X1g  = ws + 14155776;                             // fp32, becomes U
    unsigned short* X2th = (unsigned short*)(ws + 17301504); // tiled -X2 hi (3.15M sh)
    unsigned short* X2tl = (unsigned short*)(ws + 18874368); // tiled -X2 lo
    float* Mg   = ws + 20447232;                             // -> 22,020,096
    unsigned short* WTAfh = (unsigned short*)(ws + 14155776); // early overlay: 4864x1536 fp16
    unsigned short* WTBh  = (unsigned short*)(ws + 17891328); // early: 1664x1536 bf16
    unsigned short* WTBl  = (unsigned short*)(ws + 19169280);
    unsigned short* wcv   = (unsigned short*)(ws + 14155776); // 2048x6144 bf16 (after GEMMs)
    // region C:
    unsigned short* WG2h  = (unsigned short*)(ws + 22044672); // transient
    unsigned short* hsh   = (unsigned short*)(ws + 22634496); // transient
    unsigned short* w1h16 = (unsigned short*)(ws + 24207360); // transient
    float* bgraw = ws + 24403968;                             // transient
    unsigned short* Kth = (unsigned short*)(ws + 22044672);   // tiled K hi (after conv)
    unsigned short* Ktl = (unsigned short*)(ws + 23617536);   // tiled K lo
    float* beta  = ws + 25190400;
    float* g     = ws + 25214976;
    float* csg   = ws + 25239552;                             // -> 25,264,128
    // overlays
    unsigned short* hsbh = (unsigned short*)(ws + 9437184);
    unsigned short* hsbl = (unsigned short*)(ws + 11010048);
    unsigned short* Qth  = (unsigned short*)(ws + 6291456);   // tiled Q hi (after conv)
    unsigned short* Qtl  = (unsigned short*)(ws + 7864320);
    unsigned short* WoTh = (unsigned short*)(ws);
    unsigned short* WoTl = (unsigned short*)(ws + 1179648);
    unsigned short* onh  = (unsigned short*)(ws + 6291456);
    unsigned short* onl  = (unsigned short*)(ws + 7864320);

    const dim3 blk(256);
    const dim3 blkT(32, 8);

    // P0: hs -> bf16 hi/lo + fp16; weights: A-batch fp16, B-batch bf16 split.
    splitcast3_kernel<<<3072, blk, 0, stream>>>(hs, hsbh, hsbl, hsh, (T * HID) / 4);
    transcasth_kernel<<<dim3(48, 48), blkT, 0, stream>>>(Wq,    WTAfh,               1536, 1536);
    transcasth_kernel<<<dim3(48, 48), blkT, 0, stream>>>(Wv,    WTAfh + 1536 * 1536, 1536, 1536);
    transcasth_kernel<<<dim3(48, 48), blkT, 0, stream>>>(Wgate, WTAfh + 3072 * 1536, 1536, 1536);
    transcasth_kernel<<<dim3(6, 48),  blkT, 0, stream>>>(Wg1,   WTAfh + 4608 * 1536, 1536, 192);
    transsplit_kernel<<<dim3(48, 48), blkT, 0, stream>>>(Wk, WTBh,               WTBl,               1536, 1536);
    transsplit_kernel<<<dim3(1, 48),  blkT, 0, stream>>>(Wb, WTBh + 1536 * 1536, WTBl + 1536 * 1536, 1536, 12);
    transsplit_kernel<<<dim3(1, 48),  blkT, 0, stream>>>(Wa, WTBh + 1548 * 1536, WTBl + 1548 * 1536, 1536, 12);
    transcasth_kernel<<<dim3(192, 6), blkT, 0, stream>>>(Wg2, WG2h, 192, 6144);

    // P1: GEMM-A (single fp16): q|v|gate|w1 ; GEMM-B (3-term bf16): k|bg
    mgemm<1, 0><<<dim3(38, 16), blk, 0, stream>>>(hsh, nullptr, WTAfh, nullptr, 1536, 4864,
        nullptr, nullptr, q, vpre, nullptr, gsil, w1h16, nullptr);
    mgemm<2, 1><<<dim3(13, 16), blk, 0, stream>>>(hsbh, hsbl, WTBh, WTBl, 1536, 1664,
        nullptr, nullptr, nullptr, nullptr, kbuf, nullptr, nullptr, bgraw);
    bg2_kernel<<<192, blk, 0, stream>>>(bgraw, A_log, dt_bias, beta, g);

    // P2: conv weights GEMM (single fp16, bf16 out) + conv
    mgemm<3, 0><<<dim3(48, 16), blk, 0, stream>>>(w1h16, nullptr, WG2h, nullptr, 192, 6144,
        nullptr, wcv, nullptr, nullptr, nullptr, nullptr, nullptr, nullptr);
    conv_kernel<<<(T * HID) / 256, blk, 0, stream>>>(vpre, wcv, vbuf);

    // P3: chunked delta rule
    chunkloc_kernel<<<dim3(NC, NH), blk, 0, stream>>>(q, kbuf, vbuf, g, beta,
                                                      X1g, X2th, X2tl, Mg, csg);
    prep_kernel<<<dim3(NC, NH), blk, 0, stream>>>(q, kbuf, Qth, Qtl, Kth, Ktl);
    state_kernel<<<dim3(NH, 8), blk, 0, stream>>>(Qth, Qtl, Kth, Ktl, X2th, X2tl,
                                                  X1g, csg, vbuf);
    transsplit_kernel<<<dim3(48, 48), blkT, 0, stream>>>(Wo, WoTh, WoTl, 1536, 1536);
    outk_kernel<<<dim3(NC, NH, 2), blk, 0, stream>>>(X1g, Mg, vbuf);

    // P4: norm + output GEMM (3-term bf16)
    normgate_kernel<<<6144, blk, 0, stream>>>(vbuf, gsil, norm_w, onh, onl);
    mgemm<0, 1><<<dim3(12, 16), blk, 0, stream>>>(onh, onl, WoTh, WoTl, 1536, 1536,
        (float*)d_out, nullptr, nullptr, nullptr, nullptr, nullptr, nullptr, nullptr);
}